// Round 1
// baseline (287.588 us; speedup 1.0000x reference)
//
#include <hip/hip_runtime.h>

typedef unsigned short u16;
typedef unsigned int   u32;
typedef __attribute__((ext_vector_type(4))) unsigned int u32x4;
typedef __attribute__((ext_vector_type(2))) unsigned int u32x2;
typedef __attribute__((ext_vector_type(8))) short        s16x8;
typedef __attribute__((ext_vector_type(4))) float        f32x4;

#define S_LEN 4096
#define NHEAD 16
#define HDIM  64

__device__ __forceinline__ u16 f2bf(float f) {
    u32 u = __builtin_bit_cast(u32, f);
    u32 r = (u + 0x7fffu + ((u >> 16) & 1u)) >> 16;
    return (u16)r;
}
__device__ __forceinline__ float bflo(u32 w) { return __builtin_bit_cast(float, w << 16); }
__device__ __forceinline__ float bfhi(u32 w) { return __builtin_bit_cast(float, w & 0xffff0000u); }

// ---------------- fp32 -> bf16 cast (vectorized) ----------------
__global__ __launch_bounds__(256)
void cvt_f32_bf16(const float* __restrict__ in, u16* __restrict__ out, int n4) {
    int i = blockIdx.x * 256 + threadIdx.x;
    if (i >= n4) return;
    const f32x4 v = *(const f32x4*)(in + (size_t)i * 4);
    u32x2 o;
    o.x = (u32)f2bf(v.x) | ((u32)f2bf(v.y) << 16);
    o.y = (u32)f2bf(v.z) | ((u32)f2bf(v.w) << 16);
    *(u32x2*)(out + (size_t)i * 4) = o;
}

// ---------------- bf16 GEMM: C[M,N] = A[M,K] * B[N,K]^T ----------------
// 128x128 tile, BK=64, 256 thr (4 waves as 2x2 of 64x64), mfma 16x16x32 bf16.
// LDS chunks (8 bf16 = 16B) XOR-swizzled by row&7 -> conflict-free b128.
template<int OUT_BF16>
__global__ __launch_bounds__(256)
void gemm_bt(const u16* __restrict__ A, const u16* __restrict__ Bw,
             void* __restrict__ Cv, int M, int N, int K) {
    __shared__ __align__(16) u16 As[128 * 64];
    __shared__ __align__(16) u16 Bs[128 * 64];
    const int t    = threadIdx.x;
    const int bm   = blockIdx.x << 7;
    const int bn   = blockIdx.y << 7;
    const int lane = t & 63;
    const int wr   = (t >> 7) & 1;
    const int wc   = (t >> 6) & 1;
    const int fr   = lane & 15;
    const int kg   = lane >> 4;

    f32x4 acc[4][4];
#pragma unroll
    for (int m = 0; m < 4; ++m)
#pragma unroll
        for (int n = 0; n < 4; ++n) acc[m][n] = f32x4{0.f, 0.f, 0.f, 0.f};

    const int nkt = K >> 6;
    for (int kt = 0; kt < nkt; ++kt) {
        __syncthreads();
#pragma unroll
        for (int i = 0; i < 4; ++i) {
            const int cid = t + (i << 8);
            const int row = cid >> 3;
            const int cc  = cid & 7;
            const int sc  = cc ^ (row & 7);
            *(u32x4*)(&As[row * 64 + sc * 8]) =
                *(const u32x4*)(A + (size_t)(bm + row) * K + (kt << 6) + (cc << 3));
            *(u32x4*)(&Bs[row * 64 + sc * 8]) =
                *(const u32x4*)(Bw + (size_t)(bn + row) * K + (kt << 6) + (cc << 3));
        }
        __syncthreads();
#pragma unroll
        for (int kk = 0; kk < 2; ++kk) {
            s16x8 af[4], bb[4];
#pragma unroll
            for (int m = 0; m < 4; ++m) {
                const int row = (wr << 6) + (m << 4) + fr;
                const int c   = ((kk << 2) + kg) ^ (row & 7);
                af[m] = *(const s16x8*)(&As[row * 64 + c * 8]);
            }
#pragma unroll
            for (int n = 0; n < 4; ++n) {
                const int row = (wc << 6) + (n << 4) + fr;
                const int c   = ((kk << 2) + kg) ^ (row & 7);
                bb[n] = *(const s16x8*)(&Bs[row * 64 + c * 8]);
            }
#pragma unroll
            for (int m = 0; m < 4; ++m)
#pragma unroll
                for (int n = 0; n < 4; ++n)
                    acc[m][n] = __builtin_amdgcn_mfma_f32_16x16x32_bf16(af[m], bb[n], acc[m][n], 0, 0, 0);
        }
    }

    const int crow0 = bm + (wr << 6) + (kg << 2);
    const int ccol0 = bn + (wc << 6) + fr;
#pragma unroll
    for (int m = 0; m < 4; ++m)
#pragma unroll
        for (int n = 0; n < 4; ++n)
#pragma unroll
            for (int r = 0; r < 4; ++r) {
                const size_t idx = (size_t)(crow0 + (m << 4) + r) * N + (ccol0 + (n << 4));
                if constexpr (OUT_BF16) ((u16*)Cv)[idx] = f2bf(acc[m][n][r]);
                else                    ((float*)Cv)[idx] = acc[m][n][r];
            }
}

// ---------------- RoPE (half-split rotation) on bf16 Q,K in place ----------------
__global__ __launch_bounds__(256)
void rope_kernel(u16* __restrict__ q, u16* __restrict__ k, const float* __restrict__ freqs) {
    const int idx = blockIdx.x * 256 + threadIdx.x;   // B*S*H*32 = 4194304 exact
    const int d = idx & 31;
    const int h = (idx >> 5) & 15;
    const int s = (idx >> 9) & 4095;
    const int b = idx >> 21;
    const float f = freqs[s * 32 + d];
    float sn, cs;
    sincosf(f, &sn, &cs);
    const size_t base = ((size_t)(b * S_LEN + s)) * 1024 + h * 64 + d;
    {
        float t1 = bflo((u32)q[base] | 0u) ; // bf16 -> f32 via <<16
        t1 = __builtin_bit_cast(float, ((u32)q[base]) << 16);
        float t2 = __builtin_bit_cast(float, ((u32)q[base + 32]) << 16);
        q[base]      = f2bf(t1 * cs - t2 * sn);
        q[base + 32] = f2bf(t2 * cs + t1 * sn);
    }
    {
        float t1 = __builtin_bit_cast(float, ((u32)k[base]) << 16);
        float t2 = __builtin_bit_cast(float, ((u32)k[base + 32]) << 16);
        k[base]      = f2bf(t1 * cs - t2 * sn);
        k[base + 32] = f2bf(t2 * cs + t1 * sn);
    }
}

// ---------------- sliding-window attention, fp32 SIMT ----------------
// block = (b, h, 64-query chunk); 256 thr = 64 queries x 4 lanes (16 dims each).
// K/V window [qs-64, qs+127] staged in LDS (bf16, XOR-swizzled 16B chunks).
__global__ __launch_bounds__(256)
void attn_kernel(const u16* __restrict__ Q, const u16* __restrict__ K,
                 const u16* __restrict__ V, u16* __restrict__ O) {
    __shared__ __align__(16) u16 Ks[192 * 64];
    __shared__ __align__(16) u16 Vs[192 * 64];
    const int bid = blockIdx.x;
    const int ch  = bid & 63;
    const int h   = (bid >> 6) & 15;
    const int b   = bid >> 10;
    const int qs  = ch << 6;
    const int t   = threadIdx.x;

#pragma unroll
    for (int i = 0; i < 6; ++i) {
        const int cid = t + (i << 8);            // 0..1535
        const int row = cid >> 3;                // 0..191
        const int cc  = cid & 7;
        const int kp  = qs - 64 + row;
        const int sc  = cc ^ (row & 7);
        u32x4 kd = {0u, 0u, 0u, 0u}, vd = {0u, 0u, 0u, 0u};
        if (kp >= 0 && kp < S_LEN) {
            const size_t off = ((size_t)(b * S_LEN + kp)) * 1024 + (h << 6) + (cc << 3);
            kd = *(const u32x4*)(K + off);
            vd = *(const u32x4*)(V + off);
        }
        *(u32x4*)(&Ks[row * 64 + sc * 8]) = kd;
        *(u32x4*)(&Vs[row * 64 + sc * 8]) = vd;
    }
    __syncthreads();

    const int ql = t >> 2;
    const int ln = t & 3;
    const int p  = qs + ql;
    float qv[16];
    const size_t qoff = ((size_t)(b * S_LEN + p)) * 1024 + (h << 6) + (ln << 4);
#pragma unroll
    for (int c = 0; c < 2; ++c) {
        const u32x4 dw = *(const u32x4*)(Q + qoff + (c << 3));
#pragma unroll
        for (int w2 = 0; w2 < 4; ++w2) {
            qv[c * 8 + w2 * 2 + 0] = bflo(dw[w2]);
            qv[c * 8 + w2 * 2 + 1] = bfhi(dw[w2]);
        }
    }
    float outv[16];
#pragma unroll
    for (int d = 0; d < 16; ++d) outv[d] = 0.f;
    float mx = -1e30f, lsum = 0.f;

    for (int j = 0; j < 128; ++j) {
        const int kp  = p - 64 + j;
        const int row = ql + j;
        const int r7  = row & 7;
        const int bse = row * 64;
        const u32x4 k0 = *(const u32x4*)(&Ks[bse + (((ln << 1) + 0) ^ r7) * 8]);
        const u32x4 k1 = *(const u32x4*)(&Ks[bse + (((ln << 1) + 1) ^ r7) * 8]);
        float part = 0.f;
#pragma unroll
        for (int w2 = 0; w2 < 4; ++w2) {
            part = fmaf(qv[w2 * 2 + 0],     bflo(k0[w2]), part);
            part = fmaf(qv[w2 * 2 + 1],     bfhi(k0[w2]), part);
            part = fmaf(qv[8 + w2 * 2 + 0], bflo(k1[w2]), part);
            part = fmaf(qv[8 + w2 * 2 + 1], bfhi(k1[w2]), part);
        }
        part += __shfl_xor(part, 1);
        part += __shfl_xor(part, 2);
        if (kp >= 0 && kp < S_LEN) {
            const float s = part * 0.125f;
            float pj;
            if (s > mx) {
                const float corr = __expf(mx - s);
                lsum *= corr;
#pragma unroll
                for (int d = 0; d < 16; ++d) outv[d] *= corr;
                mx = s;
                pj = 1.f;
            } else {
                pj = __expf(s - mx);
            }
            lsum += pj;
            const u32x4 v0 = *(const u32x4*)(&Vs[bse + (((ln << 1) + 0) ^ r7) * 8]);
            const u32x4 v1 = *(const u32x4*)(&Vs[bse + (((ln << 1) + 1) ^ r7) * 8]);
#pragma unroll
            for (int w2 = 0; w2 < 4; ++w2) {
                outv[w2 * 2 + 0]     = fmaf(pj, bflo(v0[w2]), outv[w2 * 2 + 0]);
                outv[w2 * 2 + 1]     = fmaf(pj, bfhi(v0[w2]), outv[w2 * 2 + 1]);
                outv[8 + w2 * 2 + 0] = fmaf(pj, bflo(v1[w2]), outv[8 + w2 * 2 + 0]);
                outv[8 + w2 * 2 + 1] = fmaf(pj, bfhi(v1[w2]), outv[8 + w2 * 2 + 1]);
            }
        }
    }
    const float inv = 1.f / lsum;
    u32x4 o0, o1;
#pragma unroll
    for (int w2 = 0; w2 < 4; ++w2) {
        o0[w2] = (u32)f2bf(outv[w2 * 2] * inv)     | ((u32)f2bf(outv[w2 * 2 + 1] * inv) << 16);
        o1[w2] = (u32)f2bf(outv[8 + w2 * 2] * inv) | ((u32)f2bf(outv[8 + w2 * 2 + 1] * inv) << 16);
    }
    *(u32x4*)(O + qoff)     = o0;
    *(u32x4*)(O + qoff + 8) = o1;
}

extern "C" void kernel_launch(void* const* d_in, const int* in_sizes, int n_in,
                              void* d_out, int out_size, void* d_ws, size_t ws_size,
                              hipStream_t stream) {
    const float* x  = (const float*)d_in[0];
    const float* fr = (const float*)d_in[1];
    const float* wq = (const float*)d_in[2];
    const float* wk = (const float*)d_in[3];
    const float* wv = (const float*)d_in[4];
    const float* wo = (const float*)d_in[5];

    // workspace layout (u16 elements)
    u16* ws  = (u16*)d_ws;
    u16* xb  = ws;                 // 8388608  (x bf16) ; reused later as attention output
    u16* wqb = xb + 8388608;       // 1048576
    u16* wkb = wqb + 1048576;
    u16* wvb = wkb + 1048576;
    u16* wob = wvb + 1048576;
    u16* qb  = wob + 1048576;      // 8388608
    u16* kb  = qb + 8388608;
    u16* vb  = kb + 8388608;
    u16* ob  = xb;                 // reuse xb after QKV GEMMs

    cvt_f32_bf16<<<8192, 256, 0, stream>>>(x, xb, 2097152);
    cvt_f32_bf16<<<1024, 256, 0, stream>>>(wq, wqb, 262144);
    cvt_f32_bf16<<<1024, 256, 0, stream>>>(wk, wkb, 262144);
    cvt_f32_bf16<<<1024, 256, 0, stream>>>(wv, wvb, 262144);
    cvt_f32_bf16<<<1024, 256, 0, stream>>>(wo, wob, 262144);

    dim3 gg(64, 8);
    gemm_bt<1><<<gg, 256, 0, stream>>>(xb, wqb, qb, 8192, 1024, 1024);
    gemm_bt<1><<<gg, 256, 0, stream>>>(xb, wkb, kb, 8192, 1024, 1024);
    gemm_bt<1><<<gg, 256, 0, stream>>>(xb, wvb, vb, 8192, 1024, 1024);

    rope_kernel<<<16384, 256, 0, stream>>>(qb, kb, fr);

    attn_kernel<<<2048, 256, 0, stream>>>(qb, kb, vb, ob);

    gemm_bt<0><<<gg, 256, 0, stream>>>(ob, wob, d_out, 8192, 1024, 1024);
}

// Round 2
// 176.337 us; speedup vs baseline: 1.6309x; 1.6309x over previous
//
#include <hip/hip_runtime.h>

typedef unsigned short u16;
typedef unsigned int   u32;
typedef __attribute__((ext_vector_type(4))) unsigned int u32x4;
typedef __attribute__((ext_vector_type(2))) unsigned int u32x2;
typedef __attribute__((ext_vector_type(8))) short        s16x8;
typedef __attribute__((ext_vector_type(4))) float        f32x4;

#define S_LEN 4096
#define NHEAD 16
#define HDIM  64

typedef const __attribute__((address_space(1))) void gas_void;
typedef __attribute__((address_space(3))) void las_void;

__device__ __forceinline__ u16 f2bf(float f) {
    u32 u = __builtin_bit_cast(u32, f);
    u32 r = (u + 0x7fffu + ((u >> 16) & 1u)) >> 16;
    return (u16)r;
}
__device__ __forceinline__ float bflo(u32 w) { return __builtin_bit_cast(float, w << 16); }
__device__ __forceinline__ float bfhi(u32 w) { return __builtin_bit_cast(float, w & 0xffff0000u); }

__device__ __forceinline__ float rmax16(float v) {
    v = fmaxf(v, __shfl_xor(v, 1));
    v = fmaxf(v, __shfl_xor(v, 2));
    v = fmaxf(v, __shfl_xor(v, 4));
    v = fmaxf(v, __shfl_xor(v, 8));
    return v;
}
__device__ __forceinline__ float rsum16(float v) {
    v += __shfl_xor(v, 1);
    v += __shfl_xor(v, 2);
    v += __shfl_xor(v, 4);
    v += __shfl_xor(v, 8);
    return v;
}

// ---------------- fp32 -> bf16 cast (vectorized) ----------------
__global__ __launch_bounds__(256)
void cvt_f32_bf16(const float* __restrict__ in, u16* __restrict__ out, int n4) {
    int i = blockIdx.x * 256 + threadIdx.x;
    if (i >= n4) return;
    const f32x4 v = *(const f32x4*)(in + (size_t)i * 4);
    u32x2 o;
    o.x = (u32)f2bf(v.x) | ((u32)f2bf(v.y) << 16);
    o.y = (u32)f2bf(v.z) | ((u32)f2bf(v.w) << 16);
    *(u32x2*)(out + (size_t)i * 4) = o;
}

// ---------------- bf16 GEMM (m97 structure): C[M,N] = A[M,K] * B[N,K]^T ----------------
// 128x128 tile, BK=64, 256 thr, linear LDS, global_load_lds width=16.
template<int OUT_BF16>
__global__ __launch_bounds__(256)
void gemm_bt(const u16* __restrict__ A, const u16* __restrict__ Bw,
             void* __restrict__ Cv, int M, int N, int K) {
    __shared__ __align__(16) u16 As[128 * 64];
    __shared__ __align__(16) u16 Bs[128 * 64];
    const int t    = threadIdx.x;
    const int bm   = blockIdx.x << 7;
    const int bn   = blockIdx.y << 7;
    const int lane = t & 63;
    const int wr   = (t >> 7) & 1;
    const int wc   = (t >> 6) & 1;
    const int fr   = lane & 15;
    const int kg   = lane >> 4;

    f32x4 acc[4][4];
#pragma unroll
    for (int m = 0; m < 4; ++m)
#pragma unroll
        for (int n = 0; n < 4; ++n) acc[m][n] = f32x4{0.f, 0.f, 0.f, 0.f};

    const int srow = t >> 3;      // + i*32
    const int scc  = t & 7;
    const int wbase = (t & 192) << 3;   // wave-uniform LDS elem base (u16), + i*2048

    const int nkt = K >> 6;
    for (int kt = 0; kt < nkt; ++kt) {
        __syncthreads();
#pragma unroll
        for (int i = 0; i < 4; ++i) {
            const int row = (i << 5) + srow;
            const u16* ga = A  + (size_t)(bm + row) * K + (kt << 6) + (scc << 3);
            const u16* gb = Bw + (size_t)(bn + row) * K + (kt << 6) + (scc << 3);
            u16* la = As + (i << 11) + wbase;
            u16* lb = Bs + (i << 11) + wbase;
            __builtin_amdgcn_global_load_lds((gas_void*)ga, (las_void*)la, 16, 0, 0);
            __builtin_amdgcn_global_load_lds((gas_void*)gb, (las_void*)lb, 16, 0, 0);
        }
        __syncthreads();
#pragma unroll
        for (int kk = 0; kk < 2; ++kk) {
            s16x8 af[4], bb[4];
#pragma unroll
            for (int m = 0; m < 4; ++m) {
                const int row = (wr << 6) + (m << 4) + fr;
                af[m] = *(const s16x8*)(&As[(row << 6) + (((kk << 2) + kg) << 3)]);
            }
#pragma unroll
            for (int n = 0; n < 4; ++n) {
                const int row = (wc << 6) + (n << 4) + fr;
                bb[n] = *(const s16x8*)(&Bs[(row << 6) + (((kk << 2) + kg) << 3)]);
            }
#pragma unroll
            for (int m = 0; m < 4; ++m)
#pragma unroll
                for (int n = 0; n < 4; ++n)
                    acc[m][n] = __builtin_amdgcn_mfma_f32_16x16x32_bf16(af[m], bb[n], acc[m][n], 0, 0, 0);
        }
    }

    const int crow0 = bm + (wr << 6) + (kg << 2);
    const int ccol0 = bn + (wc << 6) + fr;
#pragma unroll
    for (int m = 0; m < 4; ++m)
#pragma unroll
        for (int n = 0; n < 4; ++n)
#pragma unroll
            for (int r = 0; r < 4; ++r) {
                const size_t idx = (size_t)(crow0 + (m << 4) + r) * N + (ccol0 + (n << 4));
                if constexpr (OUT_BF16) ((u16*)Cv)[idx] = f2bf(acc[m][n][r]);
                else                    ((float*)Cv)[idx] = acc[m][n][r];
            }
}

// ---------------- RoPE (half-split rotation) on bf16 Q,K in place ----------------
__global__ __launch_bounds__(256)
void rope_kernel(u16* __restrict__ q, u16* __restrict__ k, const float* __restrict__ freqs) {
    const int idx = blockIdx.x * 256 + threadIdx.x;   // B*S*H*32 = 4194304 exact
    const int d = idx & 31;
    const int h = (idx >> 5) & 15;
    const int s = (idx >> 9) & 4095;
    const int b = idx >> 21;
    const float f = freqs[s * 32 + d];
    float sn, cs;
    sincosf(f, &sn, &cs);
    const size_t base = ((size_t)(b * S_LEN + s)) * 1024 + h * 64 + d;
    {
        float t1 = __builtin_bit_cast(float, ((u32)q[base]) << 16);
        float t2 = __builtin_bit_cast(float, ((u32)q[base + 32]) << 16);
        q[base]      = f2bf(t1 * cs - t2 * sn);
        q[base + 32] = f2bf(t2 * cs + t1 * sn);
    }
    {
        float t1 = __builtin_bit_cast(float, ((u32)k[base]) << 16);
        float t2 = __builtin_bit_cast(float, ((u32)k[base + 32]) << 16);
        k[base]      = f2bf(t1 * cs - t2 * sn);
        k[base + 32] = f2bf(t2 * cs + t1 * sn);
    }
}

// ---------------- sliding-window attention, MFMA ----------------
// block = (b, h, 64-query chunk), 4 waves; wave w owns queries [qs+16w, qs+16w+16).
// K window [qs-64, qs+128) in Ks (swizzled); V transposed in Vt[dim][key] (swizzled).
// Per wave: QK^T = 9 key-frags x 2 = 18 MFMA; wave-parallel softmax; P (bf16,
// zero-padded to 160 keys) written into the Ks buffer; PV = 5 x 4 = 20 MFMA.
__global__ __launch_bounds__(256)
void attn_kernel(const u16* __restrict__ Q, const u16* __restrict__ K,
                 const u16* __restrict__ V, u16* __restrict__ O) {
    __shared__ __align__(16) u16 Ks[192 * 64];   // 24 KB; reused as P[4][16][192]
    __shared__ __align__(16) u16 Vt[64 * 192];   // 24 KB
    const int bid = blockIdx.x;
    const int ch  = bid & 63;
    const int h   = (bid >> 6) & 15;
    const int b   = bid >> 10;
    const int qs  = ch << 6;
    const int t   = threadIdx.x;

    // ---- stage K (row-major, 16B chunks XOR-swizzled by row&7) ----
#pragma unroll
    for (int i = 0; i < 6; ++i) {
        const int cid = t + (i << 8);            // 0..1535
        const int row = cid >> 3;                // 0..191
        const int cc  = cid & 7;
        const int kp  = qs - 64 + row;
        const int sc  = cc ^ (row & 7);
        u32x4 kd = {0u, 0u, 0u, 0u};
        if (kp >= 0 && kp < S_LEN)
            kd = *(const u32x4*)(K + ((size_t)(b * S_LEN + kp)) * 1024 + (h << 6) + (cc << 3));
        *(u32x4*)(&Ks[(row << 6) + (sc << 3)]) = kd;
    }
    // ---- stage V transposed: Vt[d][key], chunk (key/8) ^ (d&7) ----
    if (t < 192) {
        const int kp = qs - 64 + t;
        const int tc = t >> 3;
        const int ti = t & 7;
        if (kp >= 0 && kp < S_LEN) {
            const size_t off = ((size_t)(b * S_LEN + kp)) * 1024 + (h << 6);
#pragma unroll
            for (int c = 0; c < 8; ++c) {
                const u32x4 vd = *(const u32x4*)(V + off + (c << 3));
#pragma unroll
                for (int jj = 0; jj < 4; ++jj) {
                    const int d0 = (c << 3) + (jj << 1);
                    const int d1 = d0 + 1;
                    Vt[d0 * 192 + ((tc ^ (d0 & 7)) << 3) + ti] = (u16)(vd[jj] & 0xffffu);
                    Vt[d1 * 192 + ((tc ^ (d1 & 7)) << 3) + ti] = (u16)(vd[jj] >> 16);
                }
            }
        } else {
#pragma unroll
            for (int c = 0; c < 8; ++c)
#pragma unroll
                for (int j = 0; j < 8; ++j) {
                    const int d = (c << 3) + j;
                    Vt[d * 192 + ((tc ^ (d & 7)) << 3) + ti] = 0;
                }
        }
    }
    __syncthreads();

    const int w    = t >> 6;
    const int lane = t & 63;
    const int fr   = lane & 15;
    const int kg   = lane >> 4;
    const int f7   = fr & 7;

    // ---- Q fragments from global ----
    const size_t qgoff = ((size_t)(b * S_LEN + qs + (w << 4) + fr)) * 1024 + (h << 6) + (kg << 3);
    const s16x8 qa0 = *(const s16x8*)(Q + qgoff);
    const s16x8 qa1 = *(const s16x8*)(Q + qgoff + 32);

    // ---- QK^T: 9 key fragments (window of 144 keys starting at w*16) ----
    f32x4 sfr[9];
#pragma unroll
    for (int n = 0; n < 9; ++n) {
        const int row = (w << 4) + (n << 4) + fr;          // row&7 == f7
        f32x4 a = f32x4{0.f, 0.f, 0.f, 0.f};
        const s16x8 kb0 = *(const s16x8*)(&Ks[(row << 6) + ((kg ^ f7) << 3)]);
        const s16x8 kb1 = *(const s16x8*)(&Ks[(row << 6) + (((4 + kg) ^ f7) << 3)]);
        a = __builtin_amdgcn_mfma_f32_16x16x32_bf16(qa0, kb0, a, 0, 0, 0);
        a = __builtin_amdgcn_mfma_f32_16x16x32_bf16(qa1, kb1, a, 0, 0, 0);
        sfr[n] = a;
    }

    // ---- mask + scale + wave-parallel softmax (rows q = kg*4+r, cols j = n*16+fr) ----
    const float NEG = -__builtin_inff();
    float mx[4] = {NEG, NEG, NEG, NEG};
#pragma unroll
    for (int n = 0; n < 9; ++n) {
        const int j = (n << 4) + fr;
#pragma unroll
        for (int r = 0; r < 4; ++r) {
            const int q  = (kg << 2) + r;
            const int kp = qs - 64 + (w << 4) + j;
            const bool valid = (j >= q) && (j - q < 128) && (kp >= 0) && (kp < S_LEN);
            const float s = valid ? sfr[n][r] * 0.125f : NEG;
            sfr[n][r] = s;
            mx[r] = fmaxf(mx[r], s);
        }
    }
#pragma unroll
    for (int r = 0; r < 4; ++r) mx[r] = rmax16(mx[r]);
    float ls[4] = {0.f, 0.f, 0.f, 0.f};
#pragma unroll
    for (int n = 0; n < 9; ++n)
#pragma unroll
        for (int r = 0; r < 4; ++r) {
            const float p = __expf(sfr[n][r] - mx[r]);
            sfr[n][r] = p;
            ls[r] += p;
        }
#pragma unroll
    for (int r = 0; r < 4; ++r) ls[r] = rsum16(ls[r]);

    // ---- write P (bf16) into Ks buffer, swizzled; pad keys [144,160) with 0 ----
    __syncthreads();
    u16* Pw = Ks + w * 3072;                 // 16 rows x 192
#pragma unroll
    for (int n = 0; n < 9; ++n) {
        const int j = (n << 4) + fr;
#pragma unroll
        for (int r = 0; r < 4; ++r) {
            const int q = (kg << 2) + r;
            Pw[q * 192 + (((j >> 3) ^ (q & 7)) << 3) + (j & 7)] = f2bf(sfr[n][r]);
        }
    }
    {
        const int j = 144 + fr;
#pragma unroll
        for (int r = 0; r < 4; ++r) {
            const int q = (kg << 2) + r;
            Pw[q * 192 + (((j >> 3) ^ (q & 7)) << 3) + (j & 7)] = 0;
        }
    }
    __syncthreads();

    // ---- PV: P[16 x 160] * V[160 x 64] (keys offset by w*16 in Vt) ----
    f32x4 o[4];
#pragma unroll
    for (int nf = 0; nf < 4; ++nf) o[nf] = f32x4{0.f, 0.f, 0.f, 0.f};
#pragma unroll
    for (int ks = 0; ks < 5; ++ks) {
        const s16x8 pa = *(const s16x8*)(&Pw[fr * 192 + ((((ks << 2) + kg) ^ f7) << 3)]);
#pragma unroll
        for (int nf = 0; nf < 4; ++nf) {
            const int rdim = (nf << 4) + fr;              // rdim&7 == f7
            int c = (w << 1) + (ks << 2) + kg;
            if (c > 23) c = 23;                           // clamp: P==0 there
            const s16x8 vb = *(const s16x8*)(&Vt[rdim * 192 + ((c ^ f7) << 3)]);
            o[nf] = __builtin_amdgcn_mfma_f32_16x16x32_bf16(pa, vb, o[nf], 0, 0, 0);
        }
    }

    // ---- normalize + store ----
    const size_t obase = ((size_t)(b * S_LEN + qs + (w << 4) + (kg << 2))) * 1024 + (h << 6) + fr;
#pragma unroll
    for (int r = 0; r < 4; ++r) {
        const float inv = 1.f / ls[r];
#pragma unroll
        for (int nf = 0; nf < 4; ++nf)
            O[obase + (size_t)r * 1024 + (nf << 4)] = f2bf(o[nf][r] * inv);
    }
}

extern "C" void kernel_launch(void* const* d_in, const int* in_sizes, int n_in,
                              void* d_out, int out_size, void* d_ws, size_t ws_size,
                              hipStream_t stream) {
    const float* x  = (const float*)d_in[0];
    const float* fr = (const float*)d_in[1];
    const float* wq = (const float*)d_in[2];
    const float* wk = (const float*)d_in[3];
    const float* wv = (const float*)d_in[4];
    const float* wo = (const float*)d_in[5];

    u16* ws  = (u16*)d_ws;
    u16* xb  = ws;
    u16* wqb = xb + 8388608;
    u16* wkb = wqb + 1048576;
    u16* wvb = wkb + 1048576;
    u16* wob = wvb + 1048576;
    u16* qb  = wob + 1048576;
    u16* kb  = qb + 8388608;
    u16* vb  = kb + 8388608;
    u16* ob  = xb;   // reuse xb after QKV GEMMs

    cvt_f32_bf16<<<8192, 256, 0, stream>>>(x, xb, 2097152);
    cvt_f32_bf16<<<1024, 256, 0, stream>>>(wq, wqb, 262144);
    cvt_f32_bf16<<<1024, 256, 0, stream>>>(wk, wkb, 262144);
    cvt_f32_bf16<<<1024, 256, 0, stream>>>(wv, wvb, 262144);
    cvt_f32_bf16<<<1024, 256, 0, stream>>>(wo, wob, 262144);

    dim3 gg(64, 8);
    gemm_bt<1><<<gg, 256, 0, stream>>>(xb, wqb, qb, 8192, 1024, 1024);
    gemm_bt<1><<<gg, 256, 0, stream>>>(xb, wkb, kb, 8192, 1024, 1024);
    gemm_bt<1><<<gg, 256, 0, stream>>>(xb, wvb, vb, 8192, 1024, 1024);

    rope_kernel<<<16384, 256, 0, stream>>>(qb, kb, fr);

    attn_kernel<<<2048, 256, 0, stream>>>(qb, kb, vb, ob);

    gemm_bt<0><<<gg, 256, 0, stream>>>(ob, wob, d_out, 8192, 1024, 1024);
}

// Round 3
// 160.832 us; speedup vs baseline: 1.7881x; 1.0964x over previous
//
#include <hip/hip_runtime.h>

typedef unsigned short u16;
typedef unsigned int   u32;
typedef __attribute__((ext_vector_type(4))) unsigned int u32x4;
typedef __attribute__((ext_vector_type(2))) unsigned int u32x2;
typedef __attribute__((ext_vector_type(8))) short        s16x8;
typedef __attribute__((ext_vector_type(4))) float        f32x4;
typedef __attribute__((ext_vector_type(2))) float        f32x2;

#define S_LEN 4096
#define NHEAD 16
#define HDIM  64

typedef const __attribute__((address_space(1))) void gas_void;
typedef __attribute__((address_space(3))) void las_void;

__device__ __forceinline__ u16 f2bf(float f) {
    u32 u = __builtin_bit_cast(u32, f);
    u32 r = (u + 0x7fffu + ((u >> 16) & 1u)) >> 16;
    return (u16)r;
}
__device__ __forceinline__ float bflo(u32 w) { return __builtin_bit_cast(float, w << 16); }
__device__ __forceinline__ float bfhi(u32 w) { return __builtin_bit_cast(float, w & 0xffff0000u); }

__device__ __forceinline__ float rmax16(float v) {
    v = fmaxf(v, __shfl_xor(v, 1));
    v = fmaxf(v, __shfl_xor(v, 2));
    v = fmaxf(v, __shfl_xor(v, 4));
    v = fmaxf(v, __shfl_xor(v, 8));
    return v;
}
__device__ __forceinline__ float rsum16(float v) {
    v += __shfl_xor(v, 1);
    v += __shfl_xor(v, 2);
    v += __shfl_xor(v, 4);
    v += __shfl_xor(v, 8);
    return v;
}

// ---------------- fp32 -> bf16 cast (vectorized) ----------------
__global__ __launch_bounds__(256)
void cvt_f32_bf16(const float* __restrict__ in, u16* __restrict__ out, int n4) {
    int i = blockIdx.x * 256 + threadIdx.x;
    if (i >= n4) return;
    const f32x4 v = *(const f32x4*)(in + (size_t)i * 4);
    u32x2 o;
    o.x = (u32)f2bf(v.x) | ((u32)f2bf(v.y) << 16);
    o.y = (u32)f2bf(v.z) | ((u32)f2bf(v.w) << 16);
    *(u32x2*)(out + (size_t)i * 4) = o;
}

// ---------------- all four weights -> bf16, wq/wk/wv concatenated ----------------
__global__ __launch_bounds__(256)
void cvt_weights(const float* __restrict__ wq, const float* __restrict__ wk,
                 const float* __restrict__ wv, const float* __restrict__ wo,
                 u16* __restrict__ wqkv, u16* __restrict__ wob) {
    const int i   = blockIdx.x * 256 + threadIdx.x;    // 4*262144 total
    const int sel = i >> 18;
    const int loc = i & 262143;
    const float* src = (sel == 0) ? wq : (sel == 1) ? wk : (sel == 2) ? wv : wo;
    u16* dst = (sel < 3) ? (wqkv + (size_t)sel * 1048576) : wob;
    const f32x4 v = *(const f32x4*)(src + (size_t)loc * 4);
    u32x2 o;
    o.x = (u32)f2bf(v.x) | ((u32)f2bf(v.y) << 16);
    o.y = (u32)f2bf(v.z) | ((u32)f2bf(v.w) << 16);
    *(u32x2*)(dst + (size_t)loc * 4) = o;
}

// ---------------- cos/sin table from rope_freqs (S x 32) ----------------
__global__ __launch_bounds__(256)
void rope_tab(const float* __restrict__ freqs, float* __restrict__ tab) {
    const int i = blockIdx.x * 256 + threadIdx.x;      // 131072
    const float f = freqs[i];
    float sn, cs;
    sincosf(f, &sn, &cs);
    tab[i * 2]     = cs;
    tab[i * 2 + 1] = sn;
}

// ---------------- bf16 GEMM (m97 structure): C[M,N] = A[M,K] * B[N,K]^T ----------------
// 128x128 tile, BK=64, 256 thr, linear LDS, global_load_lds width=16.
// MODE 1: fused QKV — Bw is [3072][1024]; out sel = bn>>10 into q/k/v (each ldc=1024,
//         8388608 elems apart from Cv base); RoPE applied on f32 acc for bn<2048.
// MODE 2: f32 output, ldc = N.
template<int MODE>
__global__ __launch_bounds__(256)
void gemm_bt(const u16* __restrict__ A, const u16* __restrict__ Bw,
             void* __restrict__ Cv, const float* __restrict__ cstab,
             int M, int N, int K) {
    __shared__ __align__(16) u16 As[128 * 64];
    __shared__ __align__(16) u16 Bs[128 * 64];
    const int t    = threadIdx.x;
    const int bm   = blockIdx.x << 7;
    const int bn   = blockIdx.y << 7;
    const int lane = t & 63;
    const int wr   = (t >> 7) & 1;
    const int wc   = (t >> 6) & 1;
    const int fr   = lane & 15;
    const int kg   = lane >> 4;

    f32x4 acc[4][4];
#pragma unroll
    for (int m = 0; m < 4; ++m)
#pragma unroll
        for (int n = 0; n < 4; ++n) acc[m][n] = f32x4{0.f, 0.f, 0.f, 0.f};

    const int srow  = t >> 3;            // + i*32
    const int scc   = t & 7;
    const int wbase = (t & 192) << 3;    // wave-uniform LDS elem base, + i*2048

    const int nkt = K >> 6;
    for (int kt = 0; kt < nkt; ++kt) {
        __syncthreads();
#pragma unroll
        for (int i = 0; i < 4; ++i) {
            const int row = (i << 5) + srow;
            const u16* ga = A  + (size_t)(bm + row) * K + (kt << 6) + (scc << 3);
            const u16* gb = Bw + (size_t)(bn + row) * K + (kt << 6) + (scc << 3);
            u16* la = As + (i << 11) + wbase;
            u16* lb = Bs + (i << 11) + wbase;
            __builtin_amdgcn_global_load_lds((gas_void*)ga, (las_void*)la, 16, 0, 0);
            __builtin_amdgcn_global_load_lds((gas_void*)gb, (las_void*)lb, 16, 0, 0);
        }
        __syncthreads();
#pragma unroll
        for (int kk = 0; kk < 2; ++kk) {
            s16x8 af[4], bb[4];
#pragma unroll
            for (int m = 0; m < 4; ++m) {
                const int row = (wr << 6) + (m << 4) + fr;
                af[m] = *(const s16x8*)(&As[(row << 6) + (((kk << 2) + kg) << 3)]);
            }
#pragma unroll
            for (int n = 0; n < 4; ++n) {
                const int row = (wc << 6) + (n << 4) + fr;
                bb[n] = *(const s16x8*)(&Bs[(row << 6) + (((kk << 2) + kg) << 3)]);
            }
#pragma unroll
            for (int m = 0; m < 4; ++m)
#pragma unroll
                for (int n = 0; n < 4; ++n)
                    acc[m][n] = __builtin_amdgcn_mfma_f32_16x16x32_bf16(af[m], bb[n], acc[m][n], 0, 0, 0);
        }
    }

    const int crow0 = bm + (wr << 6) + (kg << 2);
    const int bcol  = (MODE == 1) ? (bn & 1023) : bn;
    const int ccol0 = bcol + (wc << 6) + fr;
    u16* outb = (MODE == 1) ? ((u16*)Cv + (size_t)(bn >> 10) * 8388608) : nullptr;
    const bool doRope = (MODE == 1) && (bn < 2048);

#pragma unroll
    for (int m = 0; m < 4; ++m)
#pragma unroll
        for (int r = 0; r < 4; ++r) {
            const int row = crow0 + (m << 4) + r;
            float v0 = acc[m][0][r], v1 = acc[m][1][r], v2 = acc[m][2][r], v3 = acc[m][3][r];
            if constexpr (MODE == 1) {
                if (doRope) {
                    const int s = row & (S_LEN - 1);
                    const f32x2 c0 = *(const f32x2*)(cstab + (((s << 5) + fr) << 1));
                    const f32x2 c1 = *(const f32x2*)(cstab + (((s << 5) + 16 + fr) << 1));
                    const float n0 = v0 * c0.x - v2 * c0.y;
                    const float n2 = v2 * c0.x + v0 * c0.y;
                    const float n1 = v1 * c1.x - v3 * c1.y;
                    const float n3 = v3 * c1.x + v1 * c1.y;
                    v0 = n0; v1 = n1; v2 = n2; v3 = n3;
                }
                u16* op = outb + (size_t)row * 1024 + ccol0;
                op[0]  = f2bf(v0);
                op[16] = f2bf(v1);
                op[32] = f2bf(v2);
                op[48] = f2bf(v3);
            } else {
                float* op = (float*)Cv + (size_t)row * N + ccol0;
                op[0]  = v0;
                op[16] = v1;
                op[32] = v2;
                op[48] = v3;
            }
        }
}

// ---------------- sliding-window attention, MFMA ----------------
// block = (b, h, 64-query chunk), 4 waves; wave w owns queries [qs+16w, qs+16w+16).
// K window [qs-64, qs+128) in Ks (swizzled); V transposed in Vt[dim][key] (swizzled).
__global__ __launch_bounds__(256)
void attn_kernel(const u16* __restrict__ Q, const u16* __restrict__ K,
                 const u16* __restrict__ V, u16* __restrict__ O) {
    __shared__ __align__(16) u16 Ks[192 * 64];   // 24 KB; reused as P[4][16][192]
    __shared__ __align__(16) u16 Vt[64 * 192];   // 24 KB
    const int bid = blockIdx.x;
    const int ch  = bid & 63;
    const int h   = (bid >> 6) & 15;
    const int b   = bid >> 10;
    const int qs  = ch << 6;
    const int t   = threadIdx.x;

    // ---- stage K (row-major, 16B chunks XOR-swizzled by row&7) ----
#pragma unroll
    for (int i = 0; i < 6; ++i) {
        const int cid = t + (i << 8);            // 0..1535
        const int row = cid >> 3;                // 0..191
        const int cc  = cid & 7;
        const int kp  = qs - 64 + row;
        const int sc  = cc ^ (row & 7);
        u32x4 kd = {0u, 0u, 0u, 0u};
        if (kp >= 0 && kp < S_LEN)
            kd = *(const u32x4*)(K + ((size_t)(b * S_LEN + kp)) * 1024 + (h << 6) + (cc << 3));
        *(u32x4*)(&Ks[(row << 6) + (sc << 3)]) = kd;
    }
    // ---- stage V transposed: Vt[d][key], chunk (key/8) ^ (d&7) ----
    if (t < 192) {
        const int kp = qs - 64 + t;
        const int tc = t >> 3;
        const int ti = t & 7;
        if (kp >= 0 && kp < S_LEN) {
            const size_t off = ((size_t)(b * S_LEN + kp)) * 1024 + (h << 6);
#pragma unroll
            for (int c = 0; c < 8; ++c) {
                const u32x4 vd = *(const u32x4*)(V + off + (c << 3));
#pragma unroll
                for (int jj = 0; jj < 4; ++jj) {
                    const int d0 = (c << 3) + (jj << 1);
                    const int d1 = d0 + 1;
                    Vt[d0 * 192 + ((tc ^ (d0 & 7)) << 3) + ti] = (u16)(vd[jj] & 0xffffu);
                    Vt[d1 * 192 + ((tc ^ (d1 & 7)) << 3) + ti] = (u16)(vd[jj] >> 16);
                }
            }
        } else {
#pragma unroll
            for (int c = 0; c < 8; ++c)
#pragma unroll
                for (int j = 0; j < 8; ++j) {
                    const int d = (c << 3) + j;
                    Vt[d * 192 + ((tc ^ (d & 7)) << 3) + ti] = 0;
                }
        }
    }
    __syncthreads();

    const int w    = t >> 6;
    const int lane = t & 63;
    const int fr   = lane & 15;
    const int kg   = lane >> 4;
    const int f7   = fr & 7;

    // ---- Q fragments from global ----
    const size_t qgoff = ((size_t)(b * S_LEN + qs + (w << 4) + fr)) * 1024 + (h << 6) + (kg << 3);
    const s16x8 qa0 = *(const s16x8*)(Q + qgoff);
    const s16x8 qa1 = *(const s16x8*)(Q + qgoff + 32);

    // ---- QK^T: 9 key fragments (window of 144 keys starting at w*16) ----
    f32x4 sfr[9];
#pragma unroll
    for (int n = 0; n < 9; ++n) {
        const int row = (w << 4) + (n << 4) + fr;          // row&7 == f7
        f32x4 a = f32x4{0.f, 0.f, 0.f, 0.f};
        const s16x8 kb0 = *(const s16x8*)(&Ks[(row << 6) + ((kg ^ f7) << 3)]);
        const s16x8 kb1 = *(const s16x8*)(&Ks[(row << 6) + (((4 + kg) ^ f7) << 3)]);
        a = __builtin_amdgcn_mfma_f32_16x16x32_bf16(qa0, kb0, a, 0, 0, 0);
        a = __builtin_amdgcn_mfma_f32_16x16x32_bf16(qa1, kb1, a, 0, 0, 0);
        sfr[n] = a;
    }

    // ---- mask + scale + wave-parallel softmax (rows q = kg*4+r, cols j = n*16+fr) ----
    const float NEG = -__builtin_inff();
    float mx[4] = {NEG, NEG, NEG, NEG};
#pragma unroll
    for (int n = 0; n < 9; ++n) {
        const int j = (n << 4) + fr;
#pragma unroll
        for (int r = 0; r < 4; ++r) {
            const int q  = (kg << 2) + r;
            const int kp = qs - 64 + (w << 4) + j;
            const bool valid = (j >= q) && (j - q < 128) && (kp >= 0) && (kp < S_LEN);
            const float s = valid ? sfr[n][r] * 0.125f : NEG;
            sfr[n][r] = s;
            mx[r] = fmaxf(mx[r], s);
        }
    }
#pragma unroll
    for (int r = 0; r < 4; ++r) mx[r] = rmax16(mx[r]);
    float ls[4] = {0.f, 0.f, 0.f, 0.f};
#pragma unroll
    for (int n = 0; n < 9; ++n)
#pragma unroll
        for (int r = 0; r < 4; ++r) {
            const float p = __expf(sfr[n][r] - mx[r]);
            sfr[n][r] = p;
            ls[r] += p;
        }
#pragma unroll
    for (int r = 0; r < 4; ++r) ls[r] = rsum16(ls[r]);

    // ---- write P (bf16) into Ks buffer, swizzled; pad keys [144,160) with 0 ----
    __syncthreads();
    u16* Pw = Ks + w * 3072;                 // 16 rows x 192
#pragma unroll
    for (int n = 0; n < 9; ++n) {
        const int j = (n << 4) + fr;
#pragma unroll
        for (int r = 0; r < 4; ++r) {
            const int q = (kg << 2) + r;
            Pw[q * 192 + (((j >> 3) ^ (q & 7)) << 3) + (j & 7)] = f2bf(sfr[n][r]);
        }
    }
    {
        const int j = 144 + fr;
#pragma unroll
        for (int r = 0; r < 4; ++r) {
            const int q = (kg << 2) + r;
            Pw[q * 192 + (((j >> 3) ^ (q & 7)) << 3) + (j & 7)] = 0;
        }
    }
    __syncthreads();

    // ---- PV: P[16 x 160] * V[160 x 64] (keys offset by w*16 in Vt) ----
    f32x4 o[4];
#pragma unroll
    for (int nf = 0; nf < 4; ++nf) o[nf] = f32x4{0.f, 0.f, 0.f, 0.f};
#pragma unroll
    for (int ks = 0; ks < 5; ++ks) {
        const s16x8 pa = *(const s16x8*)(&Pw[fr * 192 + ((((ks << 2) + kg) ^ f7) << 3)]);
#pragma unroll
        for (int nf = 0; nf < 4; ++nf) {
            const int rdim = (nf << 4) + fr;              // rdim&7 == f7
            int c = (w << 1) + (ks << 2) + kg;
            if (c > 23) c = 23;                           // clamp: P==0 there
            const s16x8 vb = *(const s16x8*)(&Vt[rdim * 192 + ((c ^ f7) << 3)]);
            o[nf] = __builtin_amdgcn_mfma_f32_16x16x32_bf16(pa, vb, o[nf], 0, 0, 0);
        }
    }

    // ---- normalize + store ----
    const size_t obase = ((size_t)(b * S_LEN + qs + (w << 4) + (kg << 2))) * 1024 + (h << 6) + fr;
#pragma unroll
    for (int r = 0; r < 4; ++r) {
        const float inv = 1.f / ls[r];
#pragma unroll
        for (int nf = 0; nf < 4; ++nf)
            O[obase + (size_t)r * 1024 + (nf << 4)] = f2bf(o[nf][r] * inv);
    }
}

extern "C" void kernel_launch(void* const* d_in, const int* in_sizes, int n_in,
                              void* d_out, int out_size, void* d_ws, size_t ws_size,
                              hipStream_t stream) {
    const float* x  = (const float*)d_in[0];
    const float* fr = (const float*)d_in[1];
    const float* wq = (const float*)d_in[2];
    const float* wk = (const float*)d_in[3];
    const float* wv = (const float*)d_in[4];
    const float* wo = (const float*)d_in[5];

    u16* ws    = (u16*)d_ws;
    u16* xb    = ws;                       // 8388608
    u16* wqkvb = xb + 8388608;             // 3145728
    u16* wob   = wqkvb + 3145728;          // 1048576
    u16* qb    = wob + 1048576;            // 8388608  (kb, vb follow contiguously)
    u16* kb    = qb + 8388608;
    u16* vb    = kb + 8388608;
    float* cstab = (float*)(vb + 8388608); // 262144 f32 (1 MB)
    u16* ob    = xb;                       // reuse xb after QKV GEMM

    cvt_f32_bf16<<<8192, 256, 0, stream>>>(x, xb, 2097152);
    cvt_weights<<<4096, 256, 0, stream>>>(wq, wk, wv, wo, wqkvb, wob);
    rope_tab<<<512, 256, 0, stream>>>(fr, cstab);

    dim3 gqkv(64, 24);
    gemm_bt<1><<<gqkv, 256, 0, stream>>>(xb, wqkvb, qb, cstab, 8192, 3072, 1024);

    attn_kernel<<<2048, 256, 0, stream>>>(qb, kb, vb, ob);

    dim3 gout(64, 8);
    gemm_bt<2><<<gout, 256, 0, stream>>>(ob, wob, d_out, nullptr, 8192, 1024, 1024);
}

// Round 4
// 150.328 us; speedup vs baseline: 1.9131x; 1.0699x over previous
//
#include <hip/hip_runtime.h>

typedef unsigned short u16;
typedef unsigned int   u32;
typedef __attribute__((ext_vector_type(4))) unsigned int u32x4;
typedef __attribute__((ext_vector_type(2))) unsigned int u32x2;
typedef __attribute__((ext_vector_type(8))) short        s16x8;
typedef __attribute__((ext_vector_type(4))) float        f32x4;
typedef __attribute__((ext_vector_type(2))) float        f32x2;

#define S_LEN 4096

typedef const __attribute__((address_space(1))) void gas_void;
typedef __attribute__((address_space(3))) void las_void;

__device__ __forceinline__ u16 f2bf(float f) {
    u32 u = __builtin_bit_cast(u32, f);
    u32 r = (u + 0x7fffu + ((u >> 16) & 1u)) >> 16;
    return (u16)r;
}
__device__ __forceinline__ float bflo(u32 w) { return __builtin_bit_cast(float, w << 16); }
__device__ __forceinline__ float bfhi(u32 w) { return __builtin_bit_cast(float, w & 0xffff0000u); }

__device__ __forceinline__ float rmax16(float v) {
    v = fmaxf(v, __shfl_xor(v, 1));
    v = fmaxf(v, __shfl_xor(v, 2));
    v = fmaxf(v, __shfl_xor(v, 4));
    v = fmaxf(v, __shfl_xor(v, 8));
    return v;
}
__device__ __forceinline__ float rsum16(float v) {
    v += __shfl_xor(v, 1);
    v += __shfl_xor(v, 2);
    v += __shfl_xor(v, 4);
    v += __shfl_xor(v, 8);
    return v;
}

// ---------------- fp32 -> bf16 cast (vectorized) ----------------
__global__ __launch_bounds__(256)
void cvt_f32_bf16(const float* __restrict__ in, u16* __restrict__ out, int n4) {
    int i = blockIdx.x * 256 + threadIdx.x;
    if (i >= n4) return;
    const f32x4 v = *(const f32x4*)(in + (size_t)i * 4);
    u32x2 o;
    o.x = (u32)f2bf(v.x) | ((u32)f2bf(v.y) << 16);
    o.y = (u32)f2bf(v.z) | ((u32)f2bf(v.w) << 16);
    *(u32x2*)(out + (size_t)i * 4) = o;
}

// ---------------- all four weights -> bf16, wq/wk/wv concatenated ----------------
__global__ __launch_bounds__(256)
void cvt_weights(const float* __restrict__ wq, const float* __restrict__ wk,
                 const float* __restrict__ wv, const float* __restrict__ wo,
                 u16* __restrict__ wqkv, u16* __restrict__ wob) {
    const int i   = blockIdx.x * 256 + threadIdx.x;    // 4*262144 total
    const int sel = i >> 18;
    const int loc = i & 262143;
    const float* src = (sel == 0) ? wq : (sel == 1) ? wk : (sel == 2) ? wv : wo;
    u16* dst = (sel < 3) ? (wqkv + (size_t)sel * 1048576) : wob;
    const f32x4 v = *(const f32x4*)(src + (size_t)loc * 4);
    u32x2 o;
    o.x = (u32)f2bf(v.x) | ((u32)f2bf(v.y) << 16);
    o.y = (u32)f2bf(v.z) | ((u32)f2bf(v.w) << 16);
    *(u32x2*)(dst + (size_t)loc * 4) = o;
}

// ---------------- cos/sin table from rope_freqs (S x 32) ----------------
__global__ __launch_bounds__(256)
void rope_tab(const float* __restrict__ freqs, float* __restrict__ tab) {
    const int i = blockIdx.x * 256 + threadIdx.x;      // 131072
    const float f = freqs[i];
    float sn, cs;
    sincosf(f, &sn, &cs);
    tab[i * 2]     = cs;
    tab[i * 2 + 1] = sn;
}

// =====================================================================
// Deep-pipelined bf16 GEMM: C[M,N] = A[M,1024] * B[N,1024]^T
// BM=128, BN=256, BK=64, 512 thr (8 waves: wr in 0..1 x wc in 0..3),
// per-wave 64x64 out (4x4 fragments).  K = 1024 fixed (16 tiles).
// T2: chunk^(row&7) swizzle via pre-swizzled gload_lds source + swizzled reads.
// T3/T4: double-buffered LDS, 2 phases/tile, 2-tile-lookahead staging,
//        counted s_waitcnt vmcnt(6) (never 0 until drain).
// T5: s_setprio(1) around each 16-MFMA cluster.
// MODE 1: fused QKV epilogue (bf16 out, RoPE on f32 acc for cols<2048)
// MODE 2: f32 output (final projection), N=1024.
// =====================================================================
#define BARR() do { asm volatile("" ::: "memory"); __builtin_amdgcn_s_barrier(); asm volatile("" ::: "memory"); } while (0)
#define VMW(n) asm volatile("s_waitcnt vmcnt(" #n ")" ::: "memory")

template<int MODE>
__global__ __launch_bounds__(512, 2)
void gemm_bt(const u16* __restrict__ A, const u16* __restrict__ Bw,
             void* __restrict__ Cv, const float* __restrict__ cstab) {
    __shared__ __align__(16) u16 As[2][8192];    // [2][128 rows][64]
    __shared__ __align__(16) u16 Bs[2][16384];   // [2][256 rows][64]
    const int t    = threadIdx.x;
    const int bm   = blockIdx.x << 7;
    const int bn   = blockIdx.y << 8;
    const int wave = t >> 6;
    const int wr   = (wave >> 2) & 1;
    const int wc   = wave & 3;
    const int lane = t & 63;
    const int fr   = lane & 15;
    const int kg   = lane >> 4;
    const int f7   = fr & 7;
    const int wq16 = wave << 9;                  // wave-uniform LDS u16 base
    const int K    = 1024;

    const int srow = t >> 3;                     // 0..63 (row within 64-row group)
    const int cSw  = (t & 7) ^ (srow & 7);       // inverse-swizzled source chunk

    const u16* ga0 = A  + (size_t)(bm + srow) * K + (cSw << 3);
    const u16* ga1 = ga0 + (size_t)64 * K;
    const u16* gb0 = Bw + (size_t)(bn + srow) * K + (cSw << 3);
    const u16* gb1 = gb0 + (size_t)64 * K;
    const u16* gb2 = gb1 + (size_t)64 * K;
    const u16* gb3 = gb2 + (size_t)64 * K;

    f32x4 acc[4][4];
#pragma unroll
    for (int m = 0; m < 4; ++m)
#pragma unroll
        for (int n = 0; n < 4; ++n) acc[m][n] = f32x4{0.f, 0.f, 0.f, 0.f};
    s16x8 bb[4][2];

#define STAGE(cur) do { \
    __builtin_amdgcn_global_load_lds((gas_void*)ga0, (las_void*)(&As[cur][wq16]),          16, 0, 0); \
    __builtin_amdgcn_global_load_lds((gas_void*)ga1, (las_void*)(&As[cur][4096 + wq16]),   16, 0, 0); \
    __builtin_amdgcn_global_load_lds((gas_void*)gb0, (las_void*)(&Bs[cur][wq16]),          16, 0, 0); \
    __builtin_amdgcn_global_load_lds((gas_void*)gb1, (las_void*)(&Bs[cur][4096 + wq16]),   16, 0, 0); \
    __builtin_amdgcn_global_load_lds((gas_void*)gb2, (las_void*)(&Bs[cur][8192 + wq16]),   16, 0, 0); \
    __builtin_amdgcn_global_load_lds((gas_void*)gb3, (las_void*)(&Bs[cur][12288 + wq16]),  16, 0, 0); \
    ga0 += 64; ga1 += 64; gb0 += 64; gb1 += 64; gb2 += 64; gb3 += 64; \
} while (0)

#define RD_A(cur, FM, KK) (*(const s16x8*)(&As[cur][(((wr << 6) + ((FM) << 4) + fr) << 6) + (((((KK) << 2) + kg) ^ f7) << 3)]))
#define RD_B(cur, FN, KK) (*(const s16x8*)(&Bs[cur][(((wc << 6) + ((FN) << 4) + fr) << 6) + (((((KK) << 2) + kg) ^ f7) << 3)]))

#define PHASE(cur, M0, M1, RB) do { \
    const s16x8 aA = RD_A(cur, M0, 0); \
    const s16x8 aB = RD_A(cur, M0, 1); \
    const s16x8 aC = RD_A(cur, M1, 0); \
    const s16x8 aD = RD_A(cur, M1, 1); \
    if (RB) { \
        _Pragma("unroll") \
        for (int n = 0; n < 4; ++n) { bb[n][0] = RD_B(cur, n, 0); bb[n][1] = RD_B(cur, n, 1); } \
    } \
    BARR(); \
    __builtin_amdgcn_s_setprio(1); \
    _Pragma("unroll") \
    for (int n = 0; n < 4; ++n) { \
        acc[M0][n] = __builtin_amdgcn_mfma_f32_16x16x32_bf16(aA, bb[n][0], acc[M0][n], 0, 0, 0); \
        acc[M0][n] = __builtin_amdgcn_mfma_f32_16x16x32_bf16(aB, bb[n][1], acc[M0][n], 0, 0, 0); \
        acc[M1][n] = __builtin_amdgcn_mfma_f32_16x16x32_bf16(aC, bb[n][0], acc[M1][n], 0, 0, 0); \
        acc[M1][n] = __builtin_amdgcn_mfma_f32_16x16x32_bf16(aD, bb[n][1], acc[M1][n], 0, 0, 0); \
    } \
    __builtin_amdgcn_s_setprio(0); \
    BARR(); \
} while (0)

    // prologue: tiles 0,1 in flight; wait tile 0 only (counted)
    STAGE(0);
    STAGE(1);
    VMW(6);
    BARR();

#pragma unroll 1
    for (int j = 0; j < 16; j += 2) {
        // tile j (buf 0)
        PHASE(0, 0, 1, 1);
        PHASE(0, 2, 3, 0);
        if (j <= 13) { STAGE(0); VMW(6); BARR(); }   // stage tile j+2; wait tile j+1
        else         { VMW(0); BARR(); }             // j==14: wait tile 15 (age 1 tile)
        // tile j+1 (buf 1)
        PHASE(1, 0, 1, 1);
        PHASE(1, 2, 3, 0);
        if (j + 1 <= 13) { STAGE(1); VMW(6); BARR(); }
        // j+1==15: fall through to epilogue (nothing outstanding)
    }

#undef PHASE
#undef RD_A
#undef RD_B
#undef STAGE

    // ---- epilogue ----
    if constexpr (MODE == 1) {
        const int sel   = bn >> 10;                        // 0=q,1=k,2=v
        u16* outb       = (u16*)Cv + (size_t)sel * 8388608;
        const int bcol  = (bn & 1023) + (wc << 6) + fr;
        const bool doRope = (bn < 2048);
        const int crow0 = bm + (wr << 6) + (kg << 2);
#pragma unroll
        for (int m = 0; m < 4; ++m)
#pragma unroll
            for (int r = 0; r < 4; ++r) {
                const int row = crow0 + (m << 4) + r;
                float v0 = acc[m][0][r], v1 = acc[m][1][r], v2 = acc[m][2][r], v3 = acc[m][3][r];
                if (doRope) {
                    const int s = row & (S_LEN - 1);
                    const f32x2 c0 = *(const f32x2*)(cstab + (((s << 5) + fr) << 1));
                    const f32x2 c1 = *(const f32x2*)(cstab + (((s << 5) + 16 + fr) << 1));
                    const float n0 = v0 * c0.x - v2 * c0.y;
                    const float n2 = v2 * c0.x + v0 * c0.y;
                    const float n1 = v1 * c1.x - v3 * c1.y;
                    const float n3 = v3 * c1.x + v1 * c1.y;
                    v0 = n0; v1 = n1; v2 = n2; v3 = n3;
                }
                u16* op = outb + (size_t)row * 1024 + bcol;
                op[0]  = f2bf(v0);
                op[16] = f2bf(v1);
                op[32] = f2bf(v2);
                op[48] = f2bf(v3);
            }
    } else {
        float* outf     = (float*)Cv;
        const int bcol  = bn + (wc << 6) + fr;
        const int crow0 = bm + (wr << 6) + (kg << 2);
#pragma unroll
        for (int m = 0; m < 4; ++m)
#pragma unroll
            for (int r = 0; r < 4; ++r) {
                const int row = crow0 + (m << 4) + r;
                float* op = outf + (size_t)row * 1024 + bcol;
                op[0]  = acc[m][0][r];
                op[16] = acc[m][1][r];
                op[32] = acc[m][2][r];
                op[48] = acc[m][3][r];
            }
    }
}

// ---------------- sliding-window attention, MFMA ----------------
// block = (b, h, 64-query chunk), 4 waves; wave w owns queries [qs+16w, qs+16w+16).
// K window [qs-64, qs+128) in Ks (swizzled); V transposed in Vt[dim][key] (swizzled).
__global__ __launch_bounds__(256)
void attn_kernel(const u16* __restrict__ Q, const u16* __restrict__ K,
                 const u16* __restrict__ V, u16* __restrict__ O) {
    __shared__ __align__(16) u16 Ks[192 * 64];   // 24 KB; reused as P[4][16][192]
    __shared__ __align__(16) u16 Vt[64 * 192];   // 24 KB
    const int bid = blockIdx.x;
    const int ch  = bid & 63;
    const int h   = (bid >> 6) & 15;
    const int b   = bid >> 10;
    const int qs  = ch << 6;
    const int t   = threadIdx.x;

#pragma unroll
    for (int i = 0; i < 6; ++i) {
        const int cid = t + (i << 8);            // 0..1535
        const int row = cid >> 3;                // 0..191
        const int cc  = cid & 7;
        const int kp  = qs - 64 + row;
        const int sc  = cc ^ (row & 7);
        u32x4 kd = {0u, 0u, 0u, 0u};
        if (kp >= 0 && kp < S_LEN)
            kd = *(const u32x4*)(K + ((size_t)(b * S_LEN + kp)) * 1024 + (h << 6) + (cc << 3));
        *(u32x4*)(&Ks[(row << 6) + (sc << 3)]) = kd;
    }
    if (t < 192) {
        const int kp = qs - 64 + t;
        const int tc = t >> 3;
        const int ti = t & 7;
        if (kp >= 0 && kp < S_LEN) {
            const size_t off = ((size_t)(b * S_LEN + kp)) * 1024 + (h << 6);
#pragma unroll
            for (int c = 0; c < 8; ++c) {
                const u32x4 vd = *(const u32x4*)(V + off + (c << 3));
#pragma unroll
                for (int jj = 0; jj < 4; ++jj) {
                    const int d0 = (c << 3) + (jj << 1);
                    const int d1 = d0 + 1;
                    Vt[d0 * 192 + ((tc ^ (d0 & 7)) << 3) + ti] = (u16)(vd[jj] & 0xffffu);
                    Vt[d1 * 192 + ((tc ^ (d1 & 7)) << 3) + ti] = (u16)(vd[jj] >> 16);
                }
            }
        } else {
#pragma unroll
            for (int c = 0; c < 8; ++c)
#pragma unroll
                for (int j = 0; j < 8; ++j) {
                    const int d = (c << 3) + j;
                    Vt[d * 192 + ((tc ^ (d & 7)) << 3) + ti] = 0;
                }
        }
    }
    __syncthreads();

    const int w    = t >> 6;
    const int lane = t & 63;
    const int fr   = lane & 15;
    const int kg   = lane >> 4;
    const int f7   = fr & 7;

    const size_t qgoff = ((size_t)(b * S_LEN + qs + (w << 4) + fr)) * 1024 + (h << 6) + (kg << 3);
    const s16x8 qa0 = *(const s16x8*)(Q + qgoff);
    const s16x8 qa1 = *(const s16x8*)(Q + qgoff + 32);

    f32x4 sfr[9];
#pragma unroll
    for (int n = 0; n < 9; ++n) {
        const int row = (w << 4) + (n << 4) + fr;          // row&7 == f7
        f32x4 a = f32x4{0.f, 0.f, 0.f, 0.f};
        const s16x8 kb0 = *(const s16x8*)(&Ks[(row << 6) + ((kg ^ f7) << 3)]);
        const s16x8 kb1 = *(const s16x8*)(&Ks[(row << 6) + (((4 + kg) ^ f7) << 3)]);
        a = __builtin_amdgcn_mfma_f32_16x16x32_bf16(qa0, kb0, a, 0, 0, 0);
        a = __builtin_amdgcn_mfma_f32_16x16x32_bf16(qa1, kb1, a, 0, 0, 0);
        sfr[n] = a;
    }

    const float NEG = -__builtin_inff();
    float mx[4] = {NEG, NEG, NEG, NEG};
#pragma unroll
    for (int n = 0; n < 9; ++n) {
        const int j = (n << 4) + fr;
#pragma unroll
        for (int r = 0; r < 4; ++r) {
            const int q  = (kg << 2) + r;
            const int kp = qs - 64 + (w << 4) + j;
            const bool valid = (j >= q) && (j - q < 128) && (kp >= 0) && (kp < S_LEN);
            const float s = valid ? sfr[n][r] * 0.125f : NEG;
            sfr[n][r] = s;
            mx[r] = fmaxf(mx[r], s);
        }
    }
#pragma unroll
    for (int r = 0; r < 4; ++r) mx[r] = rmax16(mx[r]);
    float ls[4] = {0.f, 0.f, 0.f, 0.f};
#pragma unroll
    for (int n = 0; n < 9; ++n)
#pragma unroll
        for (int r = 0; r < 4; ++r) {
            const float p = __expf(sfr[n][r] - mx[r]);
            sfr[n][r] = p;
            ls[r] += p;
        }
#pragma unroll
    for (int r = 0; r < 4; ++r) ls[r] = rsum16(ls[r]);

    __syncthreads();
    u16* Pw = Ks + w * 3072;                 // 16 rows x 192
#pragma unroll
    for (int n = 0; n < 9; ++n) {
        const int j = (n << 4) + fr;
#pragma unroll
        for (int r = 0; r < 4; ++r) {
            const int q = (kg << 2) + r;
            Pw[q * 192 + (((j >> 3) ^ (q & 7)) << 3) + (j & 7)] = f2bf(sfr[n][r]);
        }
    }
    {
        const int j = 144 + fr;
#pragma unroll
        for (int r = 0; r < 4; ++r) {
            const int q = (kg << 2) + r;
            Pw[q * 192 + (((j >> 3) ^ (q & 7)) << 3) + (j & 7)] = 0;
        }
    }
    __syncthreads();

    f32x4 o[4];
#pragma unroll
    for (int nf = 0; nf < 4; ++nf) o[nf] = f32x4{0.f, 0.f, 0.f, 0.f};
#pragma unroll
    for (int ks = 0; ks < 5; ++ks) {
        const s16x8 pa = *(const s16x8*)(&Pw[fr * 192 + ((((ks << 2) + kg) ^ f7) << 3)]);
#pragma unroll
        for (int nf = 0; nf < 4; ++nf) {
            const int rdim = (nf << 4) + fr;              // rdim&7 == f7
            int c = (w << 1) + (ks << 2) + kg;
            if (c > 23) c = 23;                           // clamp: P==0 there
            const s16x8 vb = *(const s16x8*)(&Vt[rdim * 192 + ((c ^ f7) << 3)]);
            o[nf] = __builtin_amdgcn_mfma_f32_16x16x32_bf16(pa, vb, o[nf], 0, 0, 0);
        }
    }

    const size_t obase = ((size_t)(b * S_LEN + qs + (w << 4) + (kg << 2))) * 1024 + (h << 6) + fr;
#pragma unroll
    for (int r = 0; r < 4; ++r) {
        const float inv = 1.f / ls[r];
#pragma unroll
        for (int nf = 0; nf < 4; ++nf)
            O[obase + (size_t)r * 1024 + (nf << 4)] = f2bf(o[nf][r] * inv);
    }
}

extern "C" void kernel_launch(void* const* d_in, const int* in_sizes, int n_in,
                              void* d_out, int out_size, void* d_ws, size_t ws_size,
                              hipStream_t stream) {
    const float* x  = (const float*)d_in[0];
    const float* fr = (const float*)d_in[1];
    const float* wq = (const float*)d_in[2];
    const float* wk = (const float*)d_in[3];
    const float* wv = (const float*)d_in[4];
    const float* wo = (const float*)d_in[5];

    u16* ws    = (u16*)d_ws;
    u16* xb    = ws;                       // 8388608
    u16* wqkvb = xb + 8388608;             // 3145728
    u16* wob   = wqkvb + 3145728;          // 1048576
    u16* qb    = wob + 1048576;            // 8388608  (kb, vb follow contiguously)
    u16* kb    = qb + 8388608;
    u16* vb    = kb + 8388608;
    float* cstab = (float*)(vb + 8388608); // 262144 f32 (1 MB)
    u16* ob    = xb;                       // reuse xb after QKV GEMM

    cvt_f32_bf16<<<8192, 256, 0, stream>>>(x, xb, 2097152);
    cvt_weights<<<4096, 256, 0, stream>>>(wq, wk, wv, wo, wqkvb, wob);
    rope_tab<<<512, 256, 0, stream>>>(fr, cstab);

    dim3 gqkv(64, 12);   // M/128 x 3072/256 = 768 blocks (3 full cohorts)
    gemm_bt<1><<<gqkv, 512, 0, stream>>>(xb, wqkvb, qb, cstab);

    attn_kernel<<<2048, 256, 0, stream>>>(qb, kb, vb, ob);

    dim3 gout(64, 4);    // M/128 x 1024/256 = 256 blocks (1 full cohort)
    gemm_bt<2><<<gout, 512, 0, stream>>>(ob, wob, d_out, nullptr);
}

// Round 5
// 142.487 us; speedup vs baseline: 2.0183x; 1.0550x over previous
//
#include <hip/hip_runtime.h>

typedef unsigned short u16;
typedef unsigned int   u32;
typedef __attribute__((ext_vector_type(4))) unsigned int u32x4;
typedef __attribute__((ext_vector_type(2))) unsigned int u32x2;
typedef __attribute__((ext_vector_type(8))) short        s16x8;
typedef __attribute__((ext_vector_type(4))) float        f32x4;
typedef __attribute__((ext_vector_type(2))) float        f32x2;

#define S_LEN 4096

typedef const __attribute__((address_space(1))) void gas_void;
typedef __attribute__((address_space(3))) void las_void;

__device__ __forceinline__ u16 f2bf(float f) {
    u32 u = __builtin_bit_cast(u32, f);
    u32 r = (u + 0x7fffu + ((u >> 16) & 1u)) >> 16;
    return (u16)r;
}
__device__ __forceinline__ float bflo(u32 w) { return __builtin_bit_cast(float, w << 16); }
__device__ __forceinline__ float bfhi(u32 w) { return __builtin_bit_cast(float, w & 0xffff0000u); }

__device__ __forceinline__ float rmax16(float v) {
    v = fmaxf(v, __shfl_xor(v, 1));
    v = fmaxf(v, __shfl_xor(v, 2));
    v = fmaxf(v, __shfl_xor(v, 4));
    v = fmaxf(v, __shfl_xor(v, 8));
    return v;
}
__device__ __forceinline__ float rsum16(float v) {
    v += __shfl_xor(v, 1);
    v += __shfl_xor(v, 2);
    v += __shfl_xor(v, 4);
    v += __shfl_xor(v, 8);
    return v;
}

// ---------------- fp32 -> bf16 cast (vectorized) ----------------
__global__ __launch_bounds__(256)
void cvt_f32_bf16(const float* __restrict__ in, u16* __restrict__ out, int n4) {
    int i = blockIdx.x * 256 + threadIdx.x;
    if (i >= n4) return;
    const f32x4 v = *(const f32x4*)(in + (size_t)i * 4);
    u32x2 o;
    o.x = (u32)f2bf(v.x) | ((u32)f2bf(v.y) << 16);
    o.y = (u32)f2bf(v.z) | ((u32)f2bf(v.w) << 16);
    *(u32x2*)(out + (size_t)i * 4) = o;
}

// ---------------- all four weights -> bf16, wq/wk/wv concatenated ----------------
__global__ __launch_bounds__(256)
void cvt_weights(const float* __restrict__ wq, const float* __restrict__ wk,
                 const float* __restrict__ wv, const float* __restrict__ wo,
                 u16* __restrict__ wqkv, u16* __restrict__ wob) {
    const int i   = blockIdx.x * 256 + threadIdx.x;    // 4*262144 total
    const int sel = i >> 18;
    const int loc = i & 262143;
    const float* src = (sel == 0) ? wq : (sel == 1) ? wk : (sel == 2) ? wv : wo;
    u16* dst = (sel < 3) ? (wqkv + (size_t)sel * 1048576) : wob;
    const f32x4 v = *(const f32x4*)(src + (size_t)loc * 4);
    u32x2 o;
    o.x = (u32)f2bf(v.x) | ((u32)f2bf(v.y) << 16);
    o.y = (u32)f2bf(v.z) | ((u32)f2bf(v.w) << 16);
    *(u32x2*)(dst + (size_t)loc * 4) = o;
}

// ---------------- cos/sin table from rope_freqs (S x 32) ----------------
__global__ __launch_bounds__(256)
void rope_tab(const float* __restrict__ freqs, float* __restrict__ tab) {
    const int i = blockIdx.x * 256 + threadIdx.x;      // 131072
    const float f = freqs[i];
    float sn, cs;
    sincosf(f, &sn, &cs);
    tab[i * 2]     = cs;
    tab[i * 2 + 1] = sn;
}

// =====================================================================
// Deep-pipelined bf16 GEMM: C[M,N] = A[M,1024] * B[N,1024]^T
// BM=128, BN=256, BK=64, 512 thr (8 waves, 64x64 out each, 4x4 frags).
// Sync discipline per m201: inline-asm ds_read issued pre-barrier,
// s_barrier, THEN s_waitcnt lgkmcnt(0) + sched_barrier(0), setprio MFMA.
// Stage: global_load_lds w16, 2-tile lookahead, counted vmcnt(6).
// =====================================================================
#define VMW(n) asm volatile("s_waitcnt vmcnt(" #n ")" ::: "memory")
#define DSR0(d, a)   asm volatile("ds_read_b128 %0, %1"              : "=v"(d) : "v"(a))
#define DSR(d, a, o) asm volatile("ds_read_b128 %0, %1 offset:" #o   : "=v"(d) : "v"(a))
#define MFMA16(a, b, c) __builtin_amdgcn_mfma_f32_16x16x32_bf16(a, b, c, 0, 0, 0)

template<int MODE>
__global__ __launch_bounds__(512, 2)
void gemm_bt(const u16* __restrict__ A, const u16* __restrict__ Bw,
             void* __restrict__ Cv, const float* __restrict__ cstab) {
    __shared__ __align__(16) u16 As[2][8192];    // [2][128 rows][64]
    __shared__ __align__(16) u16 Bs[2][16384];   // [2][256 rows][64]
    const int t    = threadIdx.x;
    const int bm   = blockIdx.x << 7;
    const int bn   = blockIdx.y << 8;
    const int wave = t >> 6;
    const int wr   = (wave >> 2) & 1;
    const int wc   = wave & 3;
    const int lane = t & 63;
    const int fr   = lane & 15;
    const int kg   = lane >> 4;
    const int f7   = fr & 7;
    const int wq16 = wave << 9;                  // wave-uniform LDS u16 base
    const int K    = 1024;

    const int srow = t >> 3;                     // 0..63 (row within 64-row group)
    const int cSw  = (t & 7) ^ (srow & 7);       // inverse-swizzled source chunk

    const u16* ga0 = A  + (size_t)(bm + srow) * K + (cSw << 3);
    const u16* ga1 = ga0 + (size_t)64 * K;
    const u16* gb0 = Bw + (size_t)(bn + srow) * K + (cSw << 3);
    const u16* gb1 = gb0 + (size_t)64 * K;
    const u16* gb2 = gb1 + (size_t)64 * K;
    const u16* gb3 = gb2 + (size_t)64 * K;

    f32x4 acc[4][4];
#pragma unroll
    for (int m = 0; m < 4; ++m)
#pragma unroll
        for (int n = 0; n < 4; ++n) acc[m][n] = f32x4{0.f, 0.f, 0.f, 0.f};

#define STAGE(cur) do { \
    __builtin_amdgcn_global_load_lds((gas_void*)ga0, (las_void*)(&As[cur][wq16]),          16, 0, 0); \
    __builtin_amdgcn_global_load_lds((gas_void*)ga1, (las_void*)(&As[cur][4096 + wq16]),   16, 0, 0); \
    __builtin_amdgcn_global_load_lds((gas_void*)gb0, (las_void*)(&Bs[cur][wq16]),          16, 0, 0); \
    __builtin_amdgcn_global_load_lds((gas_void*)gb1, (las_void*)(&Bs[cur][4096 + wq16]),   16, 0, 0); \
    __builtin_amdgcn_global_load_lds((gas_void*)gb2, (las_void*)(&Bs[cur][8192 + wq16]),   16, 0, 0); \
    __builtin_amdgcn_global_load_lds((gas_void*)gb3, (las_void*)(&Bs[cur][12288 + wq16]),  16, 0, 0); \
    ga0 += 64; ga1 += 64; gb0 += 64; gb1 += 64; gb2 += 64; gb3 += 64; \
} while (0)

// one phase: 8 ds_read_b128 (4 A + 4 B frags at kk-half KK), barrier,
// post-barrier lgkmcnt(0)+sched_barrier, 16 MFMA under setprio.
#define PHASE(KK) do { \
    const u32 ck = ((((KK) ? 4u : 0u) + (u32)kg) ^ (u32)f7) << 4; \
    const u32 aa = aT + ck; \
    const u32 ba = bT + ck; \
    s16x8 af0, af1, af2, af3, bf0, bf1, bf2, bf3; \
    DSR0(af0, aa); DSR(af1, aa, 2048); DSR(af2, aa, 4096); DSR(af3, aa, 6144); \
    DSR0(bf0, ba); DSR(bf1, ba, 2048); DSR(bf2, ba, 4096); DSR(bf3, ba, 6144); \
    __builtin_amdgcn_s_barrier(); \
    asm volatile("s_waitcnt lgkmcnt(0)" ::: "memory"); \
    __builtin_amdgcn_sched_barrier(0); \
    __builtin_amdgcn_s_setprio(1); \
    acc[0][0] = MFMA16(af0, bf0, acc[0][0]); \
    acc[1][0] = MFMA16(af1, bf0, acc[1][0]); \
    acc[2][0] = MFMA16(af2, bf0, acc[2][0]); \
    acc[3][0] = MFMA16(af3, bf0, acc[3][0]); \
    acc[0][1] = MFMA16(af0, bf1, acc[0][1]); \
    acc[1][1] = MFMA16(af1, bf1, acc[1][1]); \
    acc[2][1] = MFMA16(af2, bf1, acc[2][1]); \
    acc[3][1] = MFMA16(af3, bf1, acc[3][1]); \
    acc[0][2] = MFMA16(af0, bf2, acc[0][2]); \
    acc[1][2] = MFMA16(af1, bf2, acc[1][2]); \
    acc[2][2] = MFMA16(af2, bf2, acc[2][2]); \
    acc[3][2] = MFMA16(af3, bf2, acc[3][2]); \
    acc[0][3] = MFMA16(af0, bf3, acc[0][3]); \
    acc[1][3] = MFMA16(af1, bf3, acc[1][3]); \
    acc[2][3] = MFMA16(af2, bf3, acc[2][3]); \
    acc[3][3] = MFMA16(af3, bf3, acc[3][3]); \
    __builtin_amdgcn_s_setprio(0); \
} while (0)

    const u32 ldsA = (u32)(size_t)(las_void*)&As[0][0];
    const u32 ldsB = (u32)(size_t)(las_void*)&Bs[0][0];
    const u32 arow = (u32)(((wr << 6) + fr) << 7);   // row byte offset in A buf
    const u32 brow = (u32)(((wc << 6) + fr) << 7);   // row byte offset in B buf

    // prologue: tiles 0,1 in flight; wait tile 0 only (counted)
    STAGE(0);
    STAGE(1);
    VMW(6);
    __builtin_amdgcn_s_barrier();

#pragma unroll 1
    for (int j = 0; j < 16; ++j) {
        const u32 cur = (u32)(j & 1);
        const u32 aT = ldsA + (cur << 14) + arow;
        const u32 bT = ldsB + (cur << 15) + brow;
        PHASE(0);
        PHASE(1);
        __builtin_amdgcn_s_barrier();                 // all waves done reading buf cur
        if (j < 14)       { STAGE(cur); VMW(6); }     // stage tile j+2; wait tile j+1
        else if (j == 14) { VMW(0); }                 // wait tile 15 (issued at j=13)
        __builtin_amdgcn_s_barrier();                 // next tile's buffer ready
    }

#undef PHASE
#undef STAGE

    // ---- epilogue ----
    if constexpr (MODE == 1) {
        const int sel   = bn >> 10;                        // 0=q,1=k,2=v
        u16* outb       = (u16*)Cv + (size_t)sel * 8388608;
        const int bcol  = (bn & 1023) + (wc << 6) + fr;
        const bool doRope = (bn < 2048);
        const int crow0 = bm + (wr << 6) + (kg << 2);
#pragma unroll
        for (int m = 0; m < 4; ++m)
#pragma unroll
            for (int r = 0; r < 4; ++r) {
                const int row = crow0 + (m << 4) + r;
                float v0 = acc[m][0][r], v1 = acc[m][1][r], v2 = acc[m][2][r], v3 = acc[m][3][r];
                if (doRope) {
                    const int s = row & (S_LEN - 1);
                    const f32x2 c0 = *(const f32x2*)(cstab + (((s << 5) + fr) << 1));
                    const f32x2 c1 = *(const f32x2*)(cstab + (((s << 5) + 16 + fr) << 1));
                    const float n0 = v0 * c0.x - v2 * c0.y;
                    const float n2 = v2 * c0.x + v0 * c0.y;
                    const float n1 = v1 * c1.x - v3 * c1.y;
                    const float n3 = v3 * c1.x + v1 * c1.y;
                    v0 = n0; v1 = n1; v2 = n2; v3 = n3;
                }
                u16* op = outb + (size_t)row * 1024 + bcol;
                op[0]  = f2bf(v0);
                op[16] = f2bf(v1);
                op[32] = f2bf(v2);
                op[48] = f2bf(v3);
            }
    } else {
        float* outf     = (float*)Cv;
        const int bcol  = bn + (wc << 6) + fr;
        const int crow0 = bm + (wr << 6) + (kg << 2);
#pragma unroll
        for (int m = 0; m < 4; ++m)
#pragma unroll
            for (int r = 0; r < 4; ++r) {
                const int row = crow0 + (m << 4) + r;
                float* op = outf + (size_t)row * 1024 + bcol;
                op[0]  = acc[m][0][r];
                op[16] = acc[m][1][r];
                op[32] = acc[m][2][r];
                op[48] = acc[m][3][r];
            }
    }
}

// ---------------- sliding-window attention, MFMA ----------------
// block = (b, h, 64-query chunk), 4 waves; wave w owns queries [qs+16w, qs+16w+16).
// K window [qs-64, qs+128) in Ks (swizzled); V transposed in Vt[dim][key] (swizzled).
__global__ __launch_bounds__(256)
void attn_kernel(const u16* __restrict__ Q, const u16* __restrict__ K,
                 const u16* __restrict__ V, u16* __restrict__ O) {
    __shared__ __align__(16) u16 Ks[192 * 64];   // 24 KB; reused as P[4][16][192]
    __shared__ __align__(16) u16 Vt[64 * 192];   // 24 KB
    const int bid = blockIdx.x;
    const int ch  = bid & 63;
    const int h   = (bid >> 6) & 15;
    const int b   = bid >> 10;
    const int qs  = ch << 6;
    const int t   = threadIdx.x;

#pragma unroll
    for (int i = 0; i < 6; ++i) {
        const int cid = t + (i << 8);            // 0..1535
        const int row = cid >> 3;                // 0..191
        const int cc  = cid & 7;
        const int kp  = qs - 64 + row;
        const int sc  = cc ^ (row & 7);
        u32x4 kd = {0u, 0u, 0u, 0u};
        if (kp >= 0 && kp < S_LEN)
            kd = *(const u32x4*)(K + ((size_t)(b * S_LEN + kp)) * 1024 + (h << 6) + (cc << 3));
        *(u32x4*)(&Ks[(row << 6) + (sc << 3)]) = kd;
    }
    if (t < 192) {
        const int kp = qs - 64 + t;
        const int tc = t >> 3;
        const int ti = t & 7;
        if (kp >= 0 && kp < S_LEN) {
            const size_t off = ((size_t)(b * S_LEN + kp)) * 1024 + (h << 6);
#pragma unroll
            for (int c = 0; c < 8; ++c) {
                const u32x4 vd = *(const u32x4*)(V + off + (c << 3));
#pragma unroll
                for (int jj = 0; jj < 4; ++jj) {
                    const int d0 = (c << 3) + (jj << 1);
                    const int d1 = d0 + 1;
                    Vt[d0 * 192 + ((tc ^ (d0 & 7)) << 3) + ti] = (u16)(vd[jj] & 0xffffu);
                    Vt[d1 * 192 + ((tc ^ (d1 & 7)) << 3) + ti] = (u16)(vd[jj] >> 16);
                }
            }
        } else {
#pragma unroll
            for (int c = 0; c < 8; ++c)
#pragma unroll
                for (int j = 0; j < 8; ++j) {
                    const int d = (c << 3) + j;
                    Vt[d * 192 + ((tc ^ (d & 7)) << 3) + ti] = 0;
                }
        }
    }
    __syncthreads();

    const int w    = t >> 6;
    const int lane = t & 63;
    const int fr   = lane & 15;
    const int kg   = lane >> 4;
    const int f7   = fr & 7;

    const size_t qgoff = ((size_t)(b * S_LEN + qs + (w << 4) + fr)) * 1024 + (h << 6) + (kg << 3);
    const s16x8 qa0 = *(const s16x8*)(Q + qgoff);
    const s16x8 qa1 = *(const s16x8*)(Q + qgoff + 32);

    f32x4 sfr[9];
#pragma unroll
    for (int n = 0; n < 9; ++n) {
        const int row = (w << 4) + (n << 4) + fr;          // row&7 == f7
        f32x4 a = f32x4{0.f, 0.f, 0.f, 0.f};
        const s16x8 kb0 = *(const s16x8*)(&Ks[(row << 6) + ((kg ^ f7) << 3)]);
        const s16x8 kb1 = *(const s16x8*)(&Ks[(row << 6) + (((4 + kg) ^ f7) << 3)]);
        a = __builtin_amdgcn_mfma_f32_16x16x32_bf16(qa0, kb0, a, 0, 0, 0);
        a = __builtin_amdgcn_mfma_f32_16x16x32_bf16(qa1, kb1, a, 0, 0, 0);
        sfr[n] = a;
    }

    const float NEG = -__builtin_inff();
    float mx[4] = {NEG, NEG, NEG, NEG};
#pragma unroll
    for (int n = 0; n < 9; ++n) {
        const int j = (n << 4) + fr;
#pragma unroll
        for (int r = 0; r < 4; ++r) {
            const int q  = (kg << 2) + r;
            const int kp = qs - 64 + (w << 4) + j;
            const bool valid = (j >= q) && (j - q < 128) && (kp >= 0) && (kp < S_LEN);
            const float s = valid ? sfr[n][r] * 0.125f : NEG;
            sfr[n][r] = s;
            mx[r] = fmaxf(mx[r], s);
        }
    }
#pragma unroll
    for (int r = 0; r < 4; ++r) mx[r] = rmax16(mx[r]);
    float ls[4] = {0.f, 0.f, 0.f, 0.f};
#pragma unroll
    for (int n = 0; n < 9; ++n)
#pragma unroll
        for (int r = 0; r < 4; ++r) {
            const float p = __expf(sfr[n][r] - mx[r]);
            sfr[n][r] = p;
            ls[r] += p;
        }
#pragma unroll
    for (int r = 0; r < 4; ++r) ls[r] = rsum16(ls[r]);

    __syncthreads();
    u16* Pw = Ks + w * 3072;                 // 16 rows x 192
#pragma unroll
    for (int n = 0; n < 9; ++n) {
        const int j = (n << 4) + fr;
#pragma unroll
        for (int r = 0; r < 4; ++r) {
            const int q = (kg << 2) + r;
            Pw[q * 192 + (((j >> 3) ^ (q & 7)) << 3) + (j & 7)] = f2bf(sfr[n][r]);
        }
    }
    {
        const int j = 144 + fr;
#pragma unroll
        for (int r = 0; r < 4; ++r) {
            const int q = (kg << 2) + r;
            Pw[q * 192 + (((j >> 3) ^ (q & 7)) << 3) + (j & 7)] = 0;
        }
    }
    __syncthreads();

    f32x4 o[4];
#pragma unroll
    for (int nf = 0; nf < 4; ++nf) o[nf] = f32x4{0.f, 0.f, 0.f, 0.f};
#pragma unroll
    for (int ks = 0; ks < 5; ++ks) {
        const s16x8 pa = *(const s16x8*)(&Pw[fr * 192 + ((((ks << 2) + kg) ^ f7) << 3)]);
#pragma unroll
        for (int nf = 0; nf < 4; ++nf) {
            const int rdim = (nf << 4) + fr;              // rdim&7 == f7
            int c = (w << 1) + (ks << 2) + kg;
            if (c > 23) c = 23;                           // clamp: P==0 there
            const s16x8 vb = *(const s16x8*)(&Vt[rdim * 192 + ((c ^ f7) << 3)]);
            o[nf] = __builtin_amdgcn_mfma_f32_16x16x32_bf16(pa, vb, o[nf], 0, 0, 0);
        }
    }

    const size_t obase = ((size_t)(b * S_LEN + qs + (w << 4) + (kg << 2))) * 1024 + (h << 6) + fr;
#pragma unroll
    for (int r = 0; r < 4; ++r) {
        const float inv = 1.f / ls[r];
#pragma unroll
        for (int nf = 0; nf < 4; ++nf)
            O[obase + (size_t)r * 1024 + (nf << 4)] = f2bf(o[nf][r] * inv);
    }
}

extern "C" void kernel_launch(void* const* d_in, const int* in_sizes, int n_in,
                              void* d_out, int out_size, void* d_ws, size_t ws_size,
                              hipStream_t stream) {
    const float* x  = (const float*)d_in[0];
    const float* fr = (const float*)d_in[1];
    const float* wq = (const float*)d_in[2];
    const float* wk = (const float*)d_in[3];
    const float* wv = (const float*)d_in[4];
    const float* wo = (const float*)d_in[5];

    u16* ws    = (u16*)d_ws;
    u16* xb    = ws;                       // 8388608
    u16* wqkvb = xb + 8388608;             // 3145728
    u16* wob   = wqkvb + 3145728;          // 1048576
    u16* qb    = wob + 1048576;            // 8388608  (kb, vb follow contiguously)
    u16* kb    = qb + 8388608;
    u16* vb    = kb + 8388608;
    float* cstab = (float*)(vb + 8388608); // 262144 f32 (1 MB)
    u16* ob    = xb;                       // reuse xb after QKV GEMM

    cvt_f32_bf16<<<8192, 256, 0, stream>>>(x, xb, 2097152);
    cvt_weights<<<4096, 256, 0, stream>>>(wq, wk, wv, wo, wqkvb, wob);
    rope_tab<<<512, 256, 0, stream>>>(fr, cstab);

    dim3 gqkv(64, 12);   // M/128 x 3072/256 = 768 blocks (3 full cohorts)
    gemm_bt<1><<<gqkv, 512, 0, stream>>>(xb, wqkvb, qb, cstab);

    attn_kernel<<<2048, 256, 0, stream>>>(qb, kb, vb, ob);

    dim3 gout(64, 4);    // M/128 x 1024/256 = 256 blocks (1 full cohort)
    gemm_bt<2><<<gout, 512, 0, stream>>>(ob, wob, d_out, nullptr);
}

// Round 6
// 133.843 us; speedup vs baseline: 2.1487x; 1.0646x over previous
//
#include <hip/hip_runtime.h>

typedef unsigned short u16;
typedef unsigned int   u32;
typedef __attribute__((ext_vector_type(4))) unsigned int u32x4;
typedef __attribute__((ext_vector_type(2))) unsigned int u32x2;
typedef __attribute__((ext_vector_type(8))) short        s16x8;
typedef __attribute__((ext_vector_type(4))) float        f32x4;
typedef __attribute__((ext_vector_type(2))) float        f32x2;

#define S_LEN 4096

typedef const __attribute__((address_space(1))) void gas_void;
typedef __attribute__((address_space(3))) void las_void;

__device__ __forceinline__ u16 f2bf(float f) {
    u32 u = __builtin_bit_cast(u32, f);
    u32 r = (u + 0x7fffu + ((u >> 16) & 1u)) >> 16;
    return (u16)r;
}
__device__ __forceinline__ float bflo(u32 w) { return __builtin_bit_cast(float, w << 16); }
__device__ __forceinline__ float bfhi(u32 w) { return __builtin_bit_cast(float, w & 0xffff0000u); }

__device__ __forceinline__ float rmax16(float v) {
    v = fmaxf(v, __shfl_xor(v, 1));
    v = fmaxf(v, __shfl_xor(v, 2));
    v = fmaxf(v, __shfl_xor(v, 4));
    v = fmaxf(v, __shfl_xor(v, 8));
    return v;
}
__device__ __forceinline__ float rsum16(float v) {
    v += __shfl_xor(v, 1);
    v += __shfl_xor(v, 2);
    v += __shfl_xor(v, 4);
    v += __shfl_xor(v, 8);
    return v;
}

// ---------------- fp32 -> bf16 cast (vectorized) ----------------
__global__ __launch_bounds__(256)
void cvt_f32_bf16(const float* __restrict__ in, u16* __restrict__ out, int n4) {
    int i = blockIdx.x * 256 + threadIdx.x;
    if (i >= n4) return;
    const f32x4 v = *(const f32x4*)(in + (size_t)i * 4);
    u32x2 o;
    o.x = (u32)f2bf(v.x) | ((u32)f2bf(v.y) << 16);
    o.y = (u32)f2bf(v.z) | ((u32)f2bf(v.w) << 16);
    *(u32x2*)(out + (size_t)i * 4) = o;
}

// ---------------- all four weights -> bf16, wq/wk/wv concatenated ----------------
__global__ __launch_bounds__(256)
void cvt_weights(const float* __restrict__ wq, const float* __restrict__ wk,
                 const float* __restrict__ wv, const float* __restrict__ wo,
                 u16* __restrict__ wqkv, u16* __restrict__ wob) {
    const int i   = blockIdx.x * 256 + threadIdx.x;    // 4*262144 total
    const int sel = i >> 18;
    const int loc = i & 262143;
    const float* src = (sel == 0) ? wq : (sel == 1) ? wk : (sel == 2) ? wv : wo;
    u16* dst = (sel < 3) ? (wqkv + (size_t)sel * 1048576) : wob;
    const f32x4 v = *(const f32x4*)(src + (size_t)loc * 4);
    u32x2 o;
    o.x = (u32)f2bf(v.x) | ((u32)f2bf(v.y) << 16);
    o.y = (u32)f2bf(v.z) | ((u32)f2bf(v.w) << 16);
    *(u32x2*)(dst + (size_t)loc * 4) = o;
}

// ---------------- cos/sin table from rope_freqs (S x 32) ----------------
__global__ __launch_bounds__(256)
void rope_tab(const float* __restrict__ freqs, float* __restrict__ tab) {
    const int i = blockIdx.x * 256 + threadIdx.x;      // 131072
    const float f = freqs[i];
    float sn, cs;
    sincosf(f, &sn, &cs);
    tab[i * 2]     = cs;
    tab[i * 2 + 1] = sn;
}

// =====================================================================
// Deep-pipelined bf16 GEMM: C[M,N] = A[M,1024] * B[N,1024]^T
// BM=128, BN=256, BK=64, 512 thr (8 waves, 64x64 out each, 4x4 frags).
// Register-prefetch pipeline: two fragment sets (X/Y); tile j+1's 16
// ds_read_b128 are ISSUED before tile j's 32 MFMAs, awaited (lgkmcnt 0)
// only at the top of the next iteration. 2 barriers/tile around
// {STAGE, counted vmcnt}. gload_lds w16, 2-tile lookahead, vmcnt(6).
// =====================================================================
#define VMW(n) asm volatile("s_waitcnt vmcnt(" #n ")" ::: "memory")
#define LGKM0() do { asm volatile("s_waitcnt lgkmcnt(0)" ::: "memory"); \
                     __builtin_amdgcn_sched_barrier(0); } while (0)
#define DSR0(d, a)   asm volatile("ds_read_b128 %0, %1"              : "=v"(d) : "v"(a))
#define DSR(d, a, o) asm volatile("ds_read_b128 %0, %1 offset:" #o   : "=v"(d) : "v"(a))
#define MFMA16(a, b, c) __builtin_amdgcn_mfma_f32_16x16x32_bf16(a, b, c, 0, 0, 0)

#define FRAGS(P) s16x8 P##a0,P##a1,P##a2,P##a3,P##a4,P##a5,P##a6,P##a7, \
                       P##b0,P##b1,P##b2,P##b3,P##b4,P##b5,P##b6,P##b7

#define LOADTILE(P, CUR) do { \
    const u32 abase_ = ldsA + ((u32)(CUR) << 14) + arow; \
    const u32 bbase_ = ldsB + ((u32)(CUR) << 15) + brow; \
    const u32 aa0_ = abase_ + ck0, aa1_ = abase_ + ck1; \
    const u32 ba0_ = bbase_ + ck0, ba1_ = bbase_ + ck1; \
    DSR0(P##a0, aa0_); DSR(P##a1, aa0_, 2048); DSR(P##a2, aa0_, 4096); DSR(P##a3, aa0_, 6144); \
    DSR0(P##a4, aa1_); DSR(P##a5, aa1_, 2048); DSR(P##a6, aa1_, 4096); DSR(P##a7, aa1_, 6144); \
    DSR0(P##b0, ba0_); DSR(P##b1, ba0_, 2048); DSR(P##b2, ba0_, 4096); DSR(P##b3, ba0_, 6144); \
    DSR0(P##b4, ba1_); DSR(P##b5, ba1_, 2048); DSR(P##b6, ba1_, 4096); DSR(P##b7, ba1_, 6144); \
} while (0)

#define MFMA32(P) do { \
    __builtin_amdgcn_s_setprio(1); \
    acc[0][0]=MFMA16(P##a0,P##b0,acc[0][0]); acc[1][0]=MFMA16(P##a1,P##b0,acc[1][0]); \
    acc[2][0]=MFMA16(P##a2,P##b0,acc[2][0]); acc[3][0]=MFMA16(P##a3,P##b0,acc[3][0]); \
    acc[0][1]=MFMA16(P##a0,P##b1,acc[0][1]); acc[1][1]=MFMA16(P##a1,P##b1,acc[1][1]); \
    acc[2][1]=MFMA16(P##a2,P##b1,acc[2][1]); acc[3][1]=MFMA16(P##a3,P##b1,acc[3][1]); \
    acc[0][2]=MFMA16(P##a0,P##b2,acc[0][2]); acc[1][2]=MFMA16(P##a1,P##b2,acc[1][2]); \
    acc[2][2]=MFMA16(P##a2,P##b2,acc[2][2]); acc[3][2]=MFMA16(P##a3,P##b2,acc[3][2]); \
    acc[0][3]=MFMA16(P##a0,P##b3,acc[0][3]); acc[1][3]=MFMA16(P##a1,P##b3,acc[1][3]); \
    acc[2][3]=MFMA16(P##a2,P##b3,acc[2][3]); acc[3][3]=MFMA16(P##a3,P##b3,acc[3][3]); \
    acc[0][0]=MFMA16(P##a4,P##b4,acc[0][0]); acc[1][0]=MFMA16(P##a5,P##b4,acc[1][0]); \
    acc[2][0]=MFMA16(P##a6,P##b4,acc[2][0]); acc[3][0]=MFMA16(P##a7,P##b4,acc[3][0]); \
    acc[0][1]=MFMA16(P##a4,P##b5,acc[0][1]); acc[1][1]=MFMA16(P##a5,P##b5,acc[1][1]); \
    acc[2][1]=MFMA16(P##a6,P##b5,acc[2][1]); acc[3][1]=MFMA16(P##a7,P##b5,acc[3][1]); \
    acc[0][2]=MFMA16(P##a4,P##b6,acc[0][2]); acc[1][2]=MFMA16(P##a5,P##b6,acc[1][2]); \
    acc[2][2]=MFMA16(P##a6,P##b6,acc[2][2]); acc[3][2]=MFMA16(P##a7,P##b6,acc[3][2]); \
    acc[0][3]=MFMA16(P##a4,P##b7,acc[0][3]); acc[1][3]=MFMA16(P##a5,P##b7,acc[1][3]); \
    acc[2][3]=MFMA16(P##a6,P##b7,acc[2][3]); acc[3][3]=MFMA16(P##a7,P##b7,acc[3][3]); \
    __builtin_amdgcn_s_setprio(0); \
} while (0)

template<int MODE>
__global__ __launch_bounds__(512, 2)
void gemm_bt(const u16* __restrict__ A, const u16* __restrict__ Bw,
             void* __restrict__ Cv, const float* __restrict__ cstab) {
    __shared__ __align__(16) u16 As[2][8192];    // [2][128 rows][64]
    __shared__ __align__(16) u16 Bs[2][16384];   // [2][256 rows][64]
    const int t    = threadIdx.x;
    const int bm   = blockIdx.x << 7;
    const int bn   = blockIdx.y << 8;
    const int wave = t >> 6;
    const int wr   = (wave >> 2) & 1;
    const int wc   = wave & 3;
    const int lane = t & 63;
    const int fr   = lane & 15;
    const int kg   = lane >> 4;
    const int f7   = fr & 7;
    const int wq16 = wave << 9;                  // wave-uniform LDS u16 base
    const int K    = 1024;

    const int srow = t >> 3;                     // 0..63 (row within 64-row group)
    const int cSw  = (t & 7) ^ (srow & 7);       // inverse-swizzled source chunk

    const u16* ga0 = A  + (size_t)(bm + srow) * K + (cSw << 3);
    const u16* ga1 = ga0 + (size_t)64 * K;
    const u16* gb0 = Bw + (size_t)(bn + srow) * K + (cSw << 3);
    const u16* gb1 = gb0 + (size_t)64 * K;
    const u16* gb2 = gb1 + (size_t)64 * K;
    const u16* gb3 = gb2 + (size_t)64 * K;

    f32x4 acc[4][4];
#pragma unroll
    for (int m = 0; m < 4; ++m)
#pragma unroll
        for (int n = 0; n < 4; ++n) acc[m][n] = f32x4{0.f, 0.f, 0.f, 0.f};

    FRAGS(X);
    FRAGS(Y);

#define STAGE(cur) do { \
    __builtin_amdgcn_global_load_lds((gas_void*)ga0, (las_void*)(&As[cur][wq16]),          16, 0, 0); \
    __builtin_amdgcn_global_load_lds((gas_void*)ga1, (las_void*)(&As[cur][4096 + wq16]),   16, 0, 0); \
    __builtin_amdgcn_global_load_lds((gas_void*)gb0, (las_void*)(&Bs[cur][wq16]),          16, 0, 0); \
    __builtin_amdgcn_global_load_lds((gas_void*)gb1, (las_void*)(&Bs[cur][4096 + wq16]),   16, 0, 0); \
    __builtin_amdgcn_global_load_lds((gas_void*)gb2, (las_void*)(&Bs[cur][8192 + wq16]),   16, 0, 0); \
    __builtin_amdgcn_global_load_lds((gas_void*)gb3, (las_void*)(&Bs[cur][12288 + wq16]),  16, 0, 0); \
    ga0 += 64; ga1 += 64; gb0 += 64; gb1 += 64; gb2 += 64; gb3 += 64; \
} while (0)

    const u32 ldsA = (u32)(size_t)(las_void*)&As[0][0];
    const u32 ldsB = (u32)(size_t)(las_void*)&Bs[0][0];
    const u32 arow = (u32)(((wr << 6) + fr) << 7);   // row byte offset in A buf
    const u32 brow = (u32)(((wc << 6) + fr) << 7);   // row byte offset in B buf
    const u32 ck0  = (u32)((kg ^ f7) << 4);
    const u32 ck1  = (u32)(((4 + kg) ^ f7) << 4);

    // prologue: tiles 0,1 staged; wait tile 0 (counted); frags of tile 0 -> X
    STAGE(0);
    STAGE(1);
    VMW(6);
    __builtin_amdgcn_s_barrier();
    LOADTILE(X, 0);

#pragma unroll 1
    for (int j = 0; j < 16; j += 2) {
        // ---- even tile j: consume X, prefetch tile j+1 into Y ----
        LGKM0();                                     // X frags resident
        __builtin_amdgcn_s_barrier();                // all waves done reading buf0
        if (j < 14) { STAGE(0); VMW(6); }            // stage tile j+2; tile j+1 certified
        else        { VMW(0); }                      // j==14: tile 15 certified
        __builtin_amdgcn_s_barrier();                // buf1 (tile j+1) ready for all
        LOADTILE(Y, 1);                              // issue reads, do NOT wait
        MFMA32(X);                                   // compute tile j under the reads
        // ---- odd tile j+1: consume Y, prefetch tile j+2 into X ----
        LGKM0();                                     // Y frags resident
        if (j + 1 < 15) {
            __builtin_amdgcn_s_barrier();            // all waves done reading buf1
            if (j + 1 < 14) { STAGE(1); VMW(6); }    // stage tile j+3; tile j+2 certified
            __builtin_amdgcn_s_barrier();            // buf0 (tile j+2) ready for all
            LOADTILE(X, 0);
        }
        MFMA32(Y);
    }

#undef STAGE

    // ---- epilogue ----
    if constexpr (MODE == 1) {
        const int sel   = bn >> 10;                        // 0=q,1=k,2=v
        u16* outb       = (u16*)Cv + (size_t)sel * 8388608;
        const int bcol  = (bn & 1023) + (wc << 6) + fr;
        const bool doRope = (bn < 2048);
        const int crow0 = bm + (wr << 6) + (kg << 2);
#pragma unroll
        for (int m = 0; m < 4; ++m)
#pragma unroll
            for (int r = 0; r < 4; ++r) {
                const int row = crow0 + (m << 4) + r;
                float v0 = acc[m][0][r], v1 = acc[m][1][r], v2 = acc[m][2][r], v3 = acc[m][3][r];
                if (doRope) {
                    const int s = row & (S_LEN - 1);
                    const f32x2 c0 = *(const f32x2*)(cstab + (((s << 5) + fr) << 1));
                    const f32x2 c1 = *(const f32x2*)(cstab + (((s << 5) + 16 + fr) << 1));
                    const float n0 = v0 * c0.x - v2 * c0.y;
                    const float n2 = v2 * c0.x + v0 * c0.y;
                    const float n1 = v1 * c1.x - v3 * c1.y;
                    const float n3 = v3 * c1.x + v1 * c1.y;
                    v0 = n0; v1 = n1; v2 = n2; v3 = n3;
                }
                u16* op = outb + (size_t)row * 1024 + bcol;
                op[0]  = f2bf(v0);
                op[16] = f2bf(v1);
                op[32] = f2bf(v2);
                op[48] = f2bf(v3);
            }
    } else {
        float* outf     = (float*)Cv;
        const int bcol  = bn + (wc << 6) + fr;
        const int crow0 = bm + (wr << 6) + (kg << 2);
#pragma unroll
        for (int m = 0; m < 4; ++m)
#pragma unroll
            for (int r = 0; r < 4; ++r) {
                const int row = crow0 + (m << 4) + r;
                float* op = outf + (size_t)row * 1024 + bcol;
                op[0]  = acc[m][0][r];
                op[16] = acc[m][1][r];
                op[32] = acc[m][2][r];
                op[48] = acc[m][3][r];
            }
    }
}

// ---------------- sliding-window attention, MFMA ----------------
// block = (b, h, 64-query chunk), 4 waves; wave w owns queries [qs+16w, qs+16w+16).
// K window [qs-64, qs+128) in Ks (swizzled); V transposed in Vt[dim][key] (swizzled).
__global__ __launch_bounds__(256)
void attn_kernel(const u16* __restrict__ Q, const u16* __restrict__ K,
                 const u16* __restrict__ V, u16* __restrict__ O) {
    __shared__ __align__(16) u16 Ks[192 * 64];   // 24 KB; reused as P[4][16][192]
    __shared__ __align__(16) u16 Vt[64 * 192];   // 24 KB
    const int bid = blockIdx.x;
    const int ch  = bid & 63;
    const int h   = (bid >> 6) & 15;
    const int b   = bid >> 10;
    const int qs  = ch << 6;
    const int t   = threadIdx.x;

#pragma unroll
    for (int i = 0; i < 6; ++i) {
        const int cid = t + (i << 8);            // 0..1535
        const int row = cid >> 3;                // 0..191
        const int cc  = cid & 7;
        const int kp  = qs - 64 + row;
        const int sc  = cc ^ (row & 7);
        u32x4 kd = {0u, 0u, 0u, 0u};
        if (kp >= 0 && kp < S_LEN)
            kd = *(const u32x4*)(K + ((size_t)(b * S_LEN + kp)) * 1024 + (h << 6) + (cc << 3));
        *(u32x4*)(&Ks[(row << 6) + (sc << 3)]) = kd;
    }
    if (t < 192) {
        const int kp = qs - 64 + t;
        const int tc = t >> 3;
        const int ti = t & 7;
        if (kp >= 0 && kp < S_LEN) {
            const size_t off = ((size_t)(b * S_LEN + kp)) * 1024 + (h << 6);
#pragma unroll
            for (int c = 0; c < 8; ++c) {
                const u32x4 vd = *(const u32x4*)(V + off + (c << 3));
#pragma unroll
                for (int jj = 0; jj < 4; ++jj) {
                    const int d0 = (c << 3) + (jj << 1);
                    const int d1 = d0 + 1;
                    Vt[d0 * 192 + ((tc ^ (d0 & 7)) << 3) + ti] = (u16)(vd[jj] & 0xffffu);
                    Vt[d1 * 192 + ((tc ^ (d1 & 7)) << 3) + ti] = (u16)(vd[jj] >> 16);
                }
            }
        } else {
#pragma unroll
            for (int c = 0; c < 8; ++c)
#pragma unroll
                for (int j = 0; j < 8; ++j) {
                    const int d = (c << 3) + j;
                    Vt[d * 192 + ((tc ^ (d & 7)) << 3) + ti] = 0;
                }
        }
    }
    __syncthreads();

    const int w    = t >> 6;
    const int lane = t & 63;
    const int fr   = lane & 15;
    const int kg   = lane >> 4;
    const int f7   = fr & 7;

    const size_t qgoff = ((size_t)(b * S_LEN + qs + (w << 4) + fr)) * 1024 + (h << 6) + (kg << 3);
    const s16x8 qa0 = *(const s16x8*)(Q + qgoff);
    const s16x8 qa1 = *(const s16x8*)(Q + qgoff + 32);

    f32x4 sfr[9];
#pragma unroll
    for (int n = 0; n < 9; ++n) {
        const int row = (w << 4) + (n << 4) + fr;          // row&7 == f7
        f32x4 a = f32x4{0.f, 0.f, 0.f, 0.f};
        const s16x8 kb0 = *(const s16x8*)(&Ks[(row << 6) + ((kg ^ f7) << 3)]);
        const s16x8 kb1 = *(const s16x8*)(&Ks[(row << 6) + (((4 + kg) ^ f7) << 3)]);
        a = __builtin_amdgcn_mfma_f32_16x16x32_bf16(qa0, kb0, a, 0, 0, 0);
        a = __builtin_amdgcn_mfma_f32_16x16x32_bf16(qa1, kb1, a, 0, 0, 0);
        sfr[n] = a;
    }

    const float NEG = -__builtin_inff();
    float mx[4] = {NEG, NEG, NEG, NEG};
#pragma unroll
    for (int n = 0; n < 9; ++n) {
        const int j = (n << 4) + fr;
#pragma unroll
        for (int r = 0; r < 4; ++r) {
            const int q  = (kg << 2) + r;
            const int kp = qs - 64 + (w << 4) + j;
            const bool valid = (j >= q) && (j - q < 128) && (kp >= 0) && (kp < S_LEN);
            const float s = valid ? sfr[n][r] * 0.125f : NEG;
            sfr[n][r] = s;
            mx[r] = fmaxf(mx[r], s);
        }
    }
#pragma unroll
    for (int r = 0; r < 4; ++r) mx[r] = rmax16(mx[r]);
    float ls[4] = {0.f, 0.f, 0.f, 0.f};
#pragma unroll
    for (int n = 0; n < 9; ++n)
#pragma unroll
        for (int r = 0; r < 4; ++r) {
            const float p = __expf(sfr[n][r] - mx[r]);
            sfr[n][r] = p;
            ls[r] += p;
        }
#pragma unroll
    for (int r = 0; r < 4; ++r) ls[r] = rsum16(ls[r]);

    __syncthreads();
    u16* Pw = Ks + w * 3072;                 // 16 rows x 192
#pragma unroll
    for (int n = 0; n < 9; ++n) {
        const int j = (n << 4) + fr;
#pragma unroll
        for (int r = 0; r < 4; ++r) {
            const int q = (kg << 2) + r;
            Pw[q * 192 + (((j >> 3) ^ (q & 7)) << 3) + (j & 7)] = f2bf(sfr[n][r]);
        }
    }
    {
        const int j = 144 + fr;
#pragma unroll
        for (int r = 0; r < 4; ++r) {
            const int q = (kg << 2) + r;
            Pw[q * 192 + (((j >> 3) ^ (q & 7)) << 3) + (j & 7)] = 0;
        }
    }
    __syncthreads();

    f32x4 o[4];
#pragma unroll
    for (int nf = 0; nf < 4; ++nf) o[nf] = f32x4{0.f, 0.f, 0.f, 0.f};
#pragma unroll
    for (int ks = 0; ks < 5; ++ks) {
        const s16x8 pa = *(const s16x8*)(&Pw[fr * 192 + ((((ks << 2) + kg) ^ f7) << 3)]);
#pragma unroll
        for (int nf = 0; nf < 4; ++nf) {
            const int rdim = (nf << 4) + fr;              // rdim&7 == f7
            int c = (w << 1) + (ks << 2) + kg;
            if (c > 23) c = 23;                           // clamp: P==0 there
            const s16x8 vb = *(const s16x8*)(&Vt[rdim * 192 + ((c ^ f7) << 3)]);
            o[nf] = __builtin_amdgcn_mfma_f32_16x16x32_bf16(pa, vb, o[nf], 0, 0, 0);
        }
    }

    const size_t obase = ((size_t)(b * S_LEN + qs + (w << 4) + (kg << 2))) * 1024 + (h << 6) + fr;
#pragma unroll
    for (int r = 0; r < 4; ++r) {
        const float inv = 1.f / ls[r];
#pragma unroll
        for (int nf = 0; nf < 4; ++nf)
            O[obase + (size_t)r * 1024 + (nf << 4)] = f2bf(o[nf][r] * inv);
    }
}

extern "C" void kernel_launch(void* const* d_in, const int* in_sizes, int n_in,
                              void* d_out, int out_size, void* d_ws, size_t ws_size,
                              hipStream_t stream) {
    const float* x  = (const float*)d_in[0];
    const float* fr = (const float*)d_in[1];
    const float* wq = (const float*)d_in[2];
    const float* wk = (const float*)d_in[3];
    const float* wv = (const float*)d_in[4];
    const float* wo = (const float*)d_in[5];

    u16* ws    = (u16*)d_ws;
    u16* xb    = ws;                       // 8388608
    u16* wqkvb = xb + 8388608;             // 3145728
    u16* wob   = wqkvb + 3145728;          // 1048576
    u16* qb    = wob + 1048576;            // 8388608  (kb, vb follow contiguously)
    u16* kb    = qb + 8388608;
    u16* vb    = kb + 8388608;
    float* cstab = (float*)(vb + 8388608); // 262144 f32 (1 MB)
    u16* ob    = xb;                       // reuse xb after QKV GEMM

    cvt_f32_bf16<<<8192, 256, 0, stream>>>(x, xb, 2097152);
    cvt_weights<<<4096, 256, 0, stream>>>(wq, wk, wv, wo, wqkvb, wob);
    rope_tab<<<512, 256, 0, stream>>>(fr, cstab);

    dim3 gqkv(64, 12);   // M/128 x 3072/256 = 768 blocks (3 full cohorts)
    gemm_bt<1><<<gqkv, 512, 0, stream>>>(xb, wqkvb, qb, cstab);

    attn_kernel<<<2048, 256, 0, stream>>>(qb, kb, vb, ob);

    dim3 gout(64, 4);    // M/128 x 1024/256 = 256 blocks (1 full cohort)
    gemm_bt<2><<<gout, 512, 0, stream>>>(ob, wob, d_out, nullptr);
}

// Round 7
// 130.207 us; speedup vs baseline: 2.2087x; 1.0279x over previous
//
#include <hip/hip_runtime.h>

typedef unsigned short u16;
typedef unsigned int   u32;
typedef __attribute__((ext_vector_type(4))) unsigned int u32x4;
typedef __attribute__((ext_vector_type(2))) unsigned int u32x2;
typedef __attribute__((ext_vector_type(8))) short        s16x8;
typedef __attribute__((ext_vector_type(4))) float        f32x4;
typedef __attribute__((ext_vector_type(2))) float        f32x2;

#define S_LEN 4096

typedef const __attribute__((address_space(1))) void gas_void;
typedef __attribute__((address_space(3))) void las_void;

__device__ __forceinline__ u16 f2bf(float f) {
    u32 u = __builtin_bit_cast(u32, f);
    u32 r = (u + 0x7fffu + ((u >> 16) & 1u)) >> 16;
    return (u16)r;
}
__device__ __forceinline__ float bflo(u32 w) { return __builtin_bit_cast(float, w << 16); }
__device__ __forceinline__ float bfhi(u32 w) { return __builtin_bit_cast(float, w & 0xffff0000u); }

__device__ __forceinline__ float rmax16(float v) {
    v = fmaxf(v, __shfl_xor(v, 1));
    v = fmaxf(v, __shfl_xor(v, 2));
    v = fmaxf(v, __shfl_xor(v, 4));
    v = fmaxf(v, __shfl_xor(v, 8));
    return v;
}
__device__ __forceinline__ float rsum16(float v) {
    v += __shfl_xor(v, 1);
    v += __shfl_xor(v, 2);
    v += __shfl_xor(v, 4);
    v += __shfl_xor(v, 8);
    return v;
}

// ---------------- fp32 -> bf16 cast (vectorized) ----------------
__global__ __launch_bounds__(256)
void cvt_f32_bf16(const float* __restrict__ in, u16* __restrict__ out, int n4) {
    int i = blockIdx.x * 256 + threadIdx.x;
    if (i >= n4) return;
    const f32x4 v = *(const f32x4*)(in + (size_t)i * 4);
    u32x2 o;
    o.x = (u32)f2bf(v.x) | ((u32)f2bf(v.y) << 16);
    o.y = (u32)f2bf(v.z) | ((u32)f2bf(v.w) << 16);
    *(u32x2*)(out + (size_t)i * 4) = o;
}

// ---------------- all four weights -> bf16, wq/wk/wv concatenated ----------------
__global__ __launch_bounds__(256)
void cvt_weights(const float* __restrict__ wq, const float* __restrict__ wk,
                 const float* __restrict__ wv, const float* __restrict__ wo,
                 u16* __restrict__ wqkv, u16* __restrict__ wob) {
    const int i   = blockIdx.x * 256 + threadIdx.x;    // 4*262144 total
    const int sel = i >> 18;
    const int loc = i & 262143;
    const float* src = (sel == 0) ? wq : (sel == 1) ? wk : (sel == 2) ? wv : wo;
    u16* dst = (sel < 3) ? (wqkv + (size_t)sel * 1048576) : wob;
    const f32x4 v = *(const f32x4*)(src + (size_t)loc * 4);
    u32x2 o;
    o.x = (u32)f2bf(v.x) | ((u32)f2bf(v.y) << 16);
    o.y = (u32)f2bf(v.z) | ((u32)f2bf(v.w) << 16);
    *(u32x2*)(dst + (size_t)loc * 4) = o;
}

// ---------------- cos/sin table from rope_freqs (S x 32) ----------------
__global__ __launch_bounds__(256)
void rope_tab(const float* __restrict__ freqs, float* __restrict__ tab) {
    const int i = blockIdx.x * 256 + threadIdx.x;      // 131072
    const float f = freqs[i];
    float sn, cs;
    sincosf(f, &sn, &cs);
    tab[i * 2]     = cs;
    tab[i * 2 + 1] = sn;
}

// =====================================================================
// Deep-pipelined bf16 GEMM: C[M,N] = A[M,1024] * B[N,1024]^T
// BM=128, BN=256, BK=64, 512 thr (8 waves, 64x64 out each, 4x4 frags).
// ONE barrier per K-tile: each wave certifies its frag-reads (lgkmcnt 0)
// and its stage-loads (vmcnt 0, issued >= 1 tile earlier) BEFORE the
// barrier; post-barrier region is pure issue: STAGE(j+2), ds_reads(j+1),
// then MFMA(j) covers all latency. Register double-buffered frags (X/Y).
// =====================================================================
#define VMW0() asm volatile("s_waitcnt vmcnt(0)" ::: "memory")
#define LGKM0() do { asm volatile("s_waitcnt lgkmcnt(0)" ::: "memory"); \
                     __builtin_amdgcn_sched_barrier(0); } while (0)
#define DSR0(d, a)   asm volatile("ds_read_b128 %0, %1"              : "=v"(d) : "v"(a))
#define DSR(d, a, o) asm volatile("ds_read_b128 %0, %1 offset:" #o   : "=v"(d) : "v"(a))
#define MFMA16(a, b, c) __builtin_amdgcn_mfma_f32_16x16x32_bf16(a, b, c, 0, 0, 0)

#define FRAGS(P) s16x8 P##a0,P##a1,P##a2,P##a3,P##a4,P##a5,P##a6,P##a7, \
                       P##b0,P##b1,P##b2,P##b3,P##b4,P##b5,P##b6,P##b7

#define LOADTILE(P, CUR) do { \
    const u32 abase_ = ldsA + ((u32)(CUR) << 14) + arow; \
    const u32 bbase_ = ldsB + ((u32)(CUR) << 15) + brow; \
    const u32 aa0_ = abase_ + ck0, aa1_ = abase_ + ck1; \
    const u32 ba0_ = bbase_ + ck0, ba1_ = bbase_ + ck1; \
    DSR0(P##a0, aa0_); DSR(P##a1, aa0_, 2048); DSR(P##a2, aa0_, 4096); DSR(P##a3, aa0_, 6144); \
    DSR0(P##a4, aa1_); DSR(P##a5, aa1_, 2048); DSR(P##a6, aa1_, 4096); DSR(P##a7, aa1_, 6144); \
    DSR0(P##b0, ba0_); DSR(P##b1, ba0_, 2048); DSR(P##b2, ba0_, 4096); DSR(P##b3, ba0_, 6144); \
    DSR0(P##b4, ba1_); DSR(P##b5, ba1_, 2048); DSR(P##b6, ba1_, 4096); DSR(P##b7, ba1_, 6144); \
} while (0)

#define MFMA32(P) do { \
    __builtin_amdgcn_s_setprio(1); \
    acc[0][0]=MFMA16(P##a0,P##b0,acc[0][0]); acc[1][0]=MFMA16(P##a1,P##b0,acc[1][0]); \
    acc[2][0]=MFMA16(P##a2,P##b0,acc[2][0]); acc[3][0]=MFMA16(P##a3,P##b0,acc[3][0]); \
    acc[0][1]=MFMA16(P##a0,P##b1,acc[0][1]); acc[1][1]=MFMA16(P##a1,P##b1,acc[1][1]); \
    acc[2][1]=MFMA16(P##a2,P##b1,acc[2][1]); acc[3][1]=MFMA16(P##a3,P##b1,acc[3][1]); \
    acc[0][2]=MFMA16(P##a0,P##b2,acc[0][2]); acc[1][2]=MFMA16(P##a1,P##b2,acc[1][2]); \
    acc[2][2]=MFMA16(P##a2,P##b2,acc[2][2]); acc[3][2]=MFMA16(P##a3,P##b2,acc[3][2]); \
    acc[0][3]=MFMA16(P##a0,P##b3,acc[0][3]); acc[1][3]=MFMA16(P##a1,P##b3,acc[1][3]); \
    acc[2][3]=MFMA16(P##a2,P##b3,acc[2][3]); acc[3][3]=MFMA16(P##a3,P##b3,acc[3][3]); \
    acc[0][0]=MFMA16(P##a4,P##b4,acc[0][0]); acc[1][0]=MFMA16(P##a5,P##b4,acc[1][0]); \
    acc[2][0]=MFMA16(P##a6,P##b4,acc[2][0]); acc[3][0]=MFMA16(P##a7,P##b4,acc[3][0]); \
    acc[0][1]=MFMA16(P##a4,P##b5,acc[0][1]); acc[1][1]=MFMA16(P##a5,P##b5,acc[1][1]); \
    acc[2][1]=MFMA16(P##a6,P##b5,acc[2][1]); acc[3][1]=MFMA16(P##a7,P##b5,acc[3][1]); \
    acc[0][2]=MFMA16(P##a4,P##b6,acc[0][2]); acc[1][2]=MFMA16(P##a5,P##b6,acc[1][2]); \
    acc[2][2]=MFMA16(P##a6,P##b6,acc[2][2]); acc[3][2]=MFMA16(P##a7,P##b6,acc[3][2]); \
    acc[0][3]=MFMA16(P##a4,P##b7,acc[0][3]); acc[1][3]=MFMA16(P##a5,P##b7,acc[1][3]); \
    acc[2][3]=MFMA16(P##a6,P##b7,acc[2][3]); acc[3][3]=MFMA16(P##a7,P##b7,acc[3][3]); \
    __builtin_amdgcn_s_setprio(0); \
} while (0)

template<int MODE>
__global__ __launch_bounds__(512, 2)
void gemm_bt(const u16* __restrict__ A, const u16* __restrict__ Bw,
             void* __restrict__ Cv, const float* __restrict__ cstab) {
    __shared__ __align__(16) u16 As[2][8192];    // [2][128 rows][64]
    __shared__ __align__(16) u16 Bs[2][16384];   // [2][256 rows][64]
    const int t    = threadIdx.x;
    const int bm   = blockIdx.x << 7;
    const int bn   = blockIdx.y << 8;
    const int wave = t >> 6;
    const int wr   = (wave >> 2) & 1;
    const int wc   = wave & 3;
    const int lane = t & 63;
    const int fr   = lane & 15;
    const int kg   = lane >> 4;
    const int f7   = fr & 7;
    const int wq16 = wave << 9;                  // wave-uniform LDS u16 base
    const int K    = 1024;

    const int srow = t >> 3;                     // 0..63 (row within 64-row group)
    const int cSw  = (t & 7) ^ (srow & 7);       // inverse-swizzled source chunk

    const u16* ga0 = A  + (size_t)(bm + srow) * K + (cSw << 3);
    const u16* ga1 = ga0 + (size_t)64 * K;
    const u16* gb0 = Bw + (size_t)(bn + srow) * K + (cSw << 3);
    const u16* gb1 = gb0 + (size_t)64 * K;
    const u16* gb2 = gb1 + (size_t)64 * K;
    const u16* gb3 = gb2 + (size_t)64 * K;

    f32x4 acc[4][4];
#pragma unroll
    for (int m = 0; m < 4; ++m)
#pragma unroll
        for (int n = 0; n < 4; ++n) acc[m][n] = f32x4{0.f, 0.f, 0.f, 0.f};

    FRAGS(X);
    FRAGS(Y);

#define STAGE(cur) do { \
    __builtin_amdgcn_global_load_lds((gas_void*)ga0, (las_void*)(&As[cur][wq16]),          16, 0, 0); \
    __builtin_amdgcn_global_load_lds((gas_void*)ga1, (las_void*)(&As[cur][4096 + wq16]),   16, 0, 0); \
    __builtin_amdgcn_global_load_lds((gas_void*)gb0, (las_void*)(&Bs[cur][wq16]),          16, 0, 0); \
    __builtin_amdgcn_global_load_lds((gas_void*)gb1, (las_void*)(&Bs[cur][4096 + wq16]),   16, 0, 0); \
    __builtin_amdgcn_global_load_lds((gas_void*)gb2, (las_void*)(&Bs[cur][8192 + wq16]),   16, 0, 0); \
    __builtin_amdgcn_global_load_lds((gas_void*)gb3, (las_void*)(&Bs[cur][12288 + wq16]),  16, 0, 0); \
    ga0 += 64; ga1 += 64; gb0 += 64; gb1 += 64; gb2 += 64; gb3 += 64; \
} while (0)

    const u32 ldsA = (u32)(size_t)(las_void*)&As[0][0];
    const u32 ldsB = (u32)(size_t)(las_void*)&Bs[0][0];
    const u32 arow = (u32)(((wr << 6) + fr) << 7);   // row byte offset in A buf
    const u32 brow = (u32)(((wc << 6) + fr) << 7);   // row byte offset in B buf
    const u32 ck0  = (u32)((kg ^ f7) << 4);
    const u32 ck1  = (u32)(((4 + kg) ^ f7) << 4);

    // prologue: stage tile 0, certify, read its frags, stage tile 1
    STAGE(0);
    VMW0();
    __builtin_amdgcn_s_barrier();
    LOADTILE(X, 0);
    STAGE(1);

    // steady state per tile: LGKM0(own frag reads, issued 1 tile ago) +
    // VMW0(own stage loads, issued 1 tile ago) -> ONE barrier -> issue
    // {STAGE j+2, ds_reads j+1} -> MFMA tile j (covers all latency).
#pragma unroll 1
    for (int j = 0; j < 16; j += 2) {
        // ---- even tile j (frags X, buf0) ----
        LGKM0();                                 // X resident
        VMW0();                                  // tile j+1 stage landed (old loads)
        __builtin_amdgcn_s_barrier();            // single rendezvous
        if (j < 14) STAGE(0);                    // tile j+2 -> buf0 (safe: post-barrier)
        LOADTILE(Y, 1);                          // tile j+1 frags
        MFMA32(X);                               // compute tile j
        // ---- odd tile j+1 (frags Y, buf1) ----
        LGKM0();                                 // Y resident
        if (j < 14) {
            VMW0();                              // tile j+2 stage landed
            __builtin_amdgcn_s_barrier();
            if (j < 13) STAGE(1);                // tile j+3 -> buf1
            LOADTILE(X, 0);                      // tile j+2 frags
        }
        MFMA32(Y);                               // compute tile j+1
    }

#undef STAGE

    // ---- epilogue ----
    if constexpr (MODE == 1) {
        const int sel   = bn >> 10;                        // 0=q,1=k,2=v
        u16* outb       = (u16*)Cv + (size_t)sel * 8388608;
        const int bcol  = (bn & 1023) + (wc << 6) + fr;
        const bool doRope = (bn < 2048);
        const int crow0 = bm + (wr << 6) + (kg << 2);
#pragma unroll
        for (int m = 0; m < 4; ++m)
#pragma unroll
            for (int r = 0; r < 4; ++r) {
                const int row = crow0 + (m << 4) + r;
                float v0 = acc[m][0][r], v1 = acc[m][1][r], v2 = acc[m][2][r], v3 = acc[m][3][r];
                if (doRope) {
                    const int s = row & (S_LEN - 1);
                    const f32x2 c0 = *(const f32x2*)(cstab + (((s << 5) + fr) << 1));
                    const f32x2 c1 = *(const f32x2*)(cstab + (((s << 5) + 16 + fr) << 1));
                    const float n0 = v0 * c0.x - v2 * c0.y;
                    const float n2 = v2 * c0.x + v0 * c0.y;
                    const float n1 = v1 * c1.x - v3 * c1.y;
                    const float n3 = v3 * c1.x + v1 * c1.y;
                    v0 = n0; v1 = n1; v2 = n2; v3 = n3;
                }
                u16* op = outb + (size_t)row * 1024 + bcol;
                op[0]  = f2bf(v0);
                op[16] = f2bf(v1);
                op[32] = f2bf(v2);
                op[48] = f2bf(v3);
            }
    } else {
        float* outf     = (float*)Cv;
        const int bcol  = bn + (wc << 6) + fr;
        const int crow0 = bm + (wr << 6) + (kg << 2);
#pragma unroll
        for (int m = 0; m < 4; ++m)
#pragma unroll
            for (int r = 0; r < 4; ++r) {
                const int row = crow0 + (m << 4) + r;
                float* op = outf + (size_t)row * 1024 + bcol;
                op[0]  = acc[m][0][r];
                op[16] = acc[m][1][r];
                op[32] = acc[m][2][r];
                op[48] = acc[m][3][r];
            }
    }
}

// ---------------- sliding-window attention, MFMA ----------------
// block = (b, h, 64-query chunk), 4 waves; wave w owns queries [qs+16w, qs+16w+16).
// K window [qs-64, qs+128) in Ks (swizzled); V transposed in Vt[dim][key] (swizzled).
__global__ __launch_bounds__(256)
void attn_kernel(const u16* __restrict__ Q, const u16* __restrict__ K,
                 const u16* __restrict__ V, u16* __restrict__ O) {
    __shared__ __align__(16) u16 Ks[192 * 64];   // 24 KB; reused as P[4][16][192]
    __shared__ __align__(16) u16 Vt[64 * 192];   // 24 KB
    const int bid = blockIdx.x;
    const int ch  = bid & 63;
    const int h   = (bid >> 6) & 15;
    const int b   = bid >> 10;
    const int qs  = ch << 6;
    const int t   = threadIdx.x;

#pragma unroll
    for (int i = 0; i < 6; ++i) {
        const int cid = t + (i << 8);            // 0..1535
        const int row = cid >> 3;                // 0..191
        const int cc  = cid & 7;
        const int kp  = qs - 64 + row;
        const int sc  = cc ^ (row & 7);
        u32x4 kd = {0u, 0u, 0u, 0u};
        if (kp >= 0 && kp < S_LEN)
            kd = *(const u32x4*)(K + ((size_t)(b * S_LEN + kp)) * 1024 + (h << 6) + (cc << 3));
        *(u32x4*)(&Ks[(row << 6) + (sc << 3)]) = kd;
    }
    if (t < 192) {
        const int kp = qs - 64 + t;
        const int tc = t >> 3;
        const int ti = t & 7;
        if (kp >= 0 && kp < S_LEN) {
            const size_t off = ((size_t)(b * S_LEN + kp)) * 1024 + (h << 6);
#pragma unroll
            for (int c = 0; c < 8; ++c) {
                const u32x4 vd = *(const u32x4*)(V + off + (c << 3));
#pragma unroll
                for (int jj = 0; jj < 4; ++jj) {
                    const int d0 = (c << 3) + (jj << 1);
                    const int d1 = d0 + 1;
                    Vt[d0 * 192 + ((tc ^ (d0 & 7)) << 3) + ti] = (u16)(vd[jj] & 0xffffu);
                    Vt[d1 * 192 + ((tc ^ (d1 & 7)) << 3) + ti] = (u16)(vd[jj] >> 16);
                }
            }
        } else {
#pragma unroll
            for (int c = 0; c < 8; ++c)
#pragma unroll
                for (int j = 0; j < 8; ++j) {
                    const int d = (c << 3) + j;
                    Vt[d * 192 + ((tc ^ (d & 7)) << 3) + ti] = 0;
                }
        }
    }
    __syncthreads();

    const int w    = t >> 6;
    const int lane = t & 63;
    const int fr   = lane & 15;
    const int kg   = lane >> 4;
    const int f7   = fr & 7;

    const size_t qgoff = ((size_t)(b * S_LEN + qs + (w << 4) + fr)) * 1024 + (h << 6) + (kg << 3);
    const s16x8 qa0 = *(const s16x8*)(Q + qgoff);
    const s16x8 qa1 = *(const s16x8*)(Q + qgoff + 32);

    f32x4 sfr[9];
#pragma unroll
    for (int n = 0; n < 9; ++n) {
        const int row = (w << 4) + (n << 4) + fr;          // row&7 == f7
        f32x4 a = f32x4{0.f, 0.f, 0.f, 0.f};
        const s16x8 kb0 = *(const s16x8*)(&Ks[(row << 6) + ((kg ^ f7) << 3)]);
        const s16x8 kb1 = *(const s16x8*)(&Ks[(row << 6) + (((4 + kg) ^ f7) << 3)]);
        a = __builtin_amdgcn_mfma_f32_16x16x32_bf16(qa0, kb0, a, 0, 0, 0);
        a = __builtin_amdgcn_mfma_f32_16x16x32_bf16(qa1, kb1, a, 0, 0, 0);
        sfr[n] = a;
    }

    const float NEG = -__builtin_inff();
    float mx[4] = {NEG, NEG, NEG, NEG};
#pragma unroll
    for (int n = 0; n < 9; ++n) {
        const int j = (n << 4) + fr;
#pragma unroll
        for (int r = 0; r < 4; ++r) {
            const int q  = (kg << 2) + r;
            const int kp = qs - 64 + (w << 4) + j;
            const bool valid = (j >= q) && (j - q < 128) && (kp >= 0) && (kp < S_LEN);
            const float s = valid ? sfr[n][r] * 0.125f : NEG;
            sfr[n][r] = s;
            mx[r] = fmaxf(mx[r], s);
        }
    }
#pragma unroll
    for (int r = 0; r < 4; ++r) mx[r] = rmax16(mx[r]);
    float ls[4] = {0.f, 0.f, 0.f, 0.f};
#pragma unroll
    for (int n = 0; n < 9; ++n)
#pragma unroll
        for (int r = 0; r < 4; ++r) {
            const float p = __expf(sfr[n][r] - mx[r]);
            sfr[n][r] = p;
            ls[r] += p;
        }
#pragma unroll
    for (int r = 0; r < 4; ++r) ls[r] = rsum16(ls[r]);

    __syncthreads();
    u16* Pw = Ks + w * 3072;                 // 16 rows x 192
#pragma unroll
    for (int n = 0; n < 9; ++n) {
        const int j = (n << 4) + fr;
#pragma unroll
        for (int r = 0; r < 4; ++r) {
            const int q = (kg << 2) + r;
            Pw[q * 192 + (((j >> 3) ^ (q & 7)) << 3) + (j & 7)] = f2bf(sfr[n][r]);
        }
    }
    {
        const int j = 144 + fr;
#pragma unroll
        for (int r = 0; r < 4; ++r) {
            const int q = (kg << 2) + r;
            Pw[q * 192 + (((j >> 3) ^ (q & 7)) << 3) + (j & 7)] = 0;
        }
    }
    __syncthreads();

    f32x4 o[4];
#pragma unroll
    for (int nf = 0; nf < 4; ++nf) o[nf] = f32x4{0.f, 0.f, 0.f, 0.f};
#pragma unroll
    for (int ks = 0; ks < 5; ++ks) {
        const s16x8 pa = *(const s16x8*)(&Pw[fr * 192 + ((((ks << 2) + kg) ^ f7) << 3)]);
#pragma unroll
        for (int nf = 0; nf < 4; ++nf) {
            const int rdim = (nf << 4) + fr;              // rdim&7 == f7
            int c = (w << 1) + (ks << 2) + kg;
            if (c > 23) c = 23;                           // clamp: P==0 there
            const s16x8 vb = *(const s16x8*)(&Vt[rdim * 192 + ((c ^ f7) << 3)]);
            o[nf] = __builtin_amdgcn_mfma_f32_16x16x32_bf16(pa, vb, o[nf], 0, 0, 0);
        }
    }

    const size_t obase = ((size_t)(b * S_LEN + qs + (w << 4) + (kg << 2))) * 1024 + (h << 6) + fr;
#pragma unroll
    for (int r = 0; r < 4; ++r) {
        const float inv = 1.f / ls[r];
#pragma unroll
        for (int nf = 0; nf < 4; ++nf)
            O[obase + (size_t)r * 1024 + (nf << 4)] = f2bf(o[nf][r] * inv);
    }
}

extern "C" void kernel_launch(void* const* d_in, const int* in_sizes, int n_in,
                              void* d_out, int out_size, void* d_ws, size_t ws_size,
                              hipStream_t stream) {
    const float* x  = (const float*)d_in[0];
    const float* fr = (const float*)d_in[1];
    const float* wq = (const float*)d_in[2];
    const float* wk = (const float*)d_in[3];
    const float* wv = (const float*)d_in[4];
    const float* wo = (const float*)d_in[5];

    u16* ws    = (u16*)d_ws;
    u16* xb    = ws;                       // 8388608
    u16* wqkvb = xb + 8388608;             // 3145728
    u16* wob   = wqkvb + 3145728;          // 1048576
    u16* qb    = wob + 1048576;            // 8388608  (kb, vb follow contiguously)
    u16* kb    = qb + 8388608;
    u16* vb    = kb + 8388608;
    float* cstab = (float*)(vb + 8388608); // 262144 f32 (1 MB)
    u16* ob    = xb;                       // reuse xb after QKV GEMM

    cvt_f32_bf16<<<8192, 256, 0, stream>>>(x, xb, 2097152);
    cvt_weights<<<4096, 256, 0, stream>>>(wq, wk, wv, wo, wqkvb, wob);
    rope_tab<<<512, 256, 0, stream>>>(fr, cstab);

    dim3 gqkv(64, 12);   // M/128 x 3072/256 = 768 blocks (3 full cohorts)
    gemm_bt<1><<<gqkv, 512, 0, stream>>>(xb, wqkvb, qb, cstab);

    attn_kernel<<<2048, 256, 0, stream>>>(qb, kb, vb, ob);

    dim3 gout(64, 4);    // M/128 x 1024/256 = 256 blocks (1 full cohort)
    gemm_bt<2><<<gout, 512, 0, stream>>>(ob, wob, d_out, nullptr);
}